// Round 1
// baseline (2076.216 us; speedup 1.0000x reference)
//
#include <hip/hip_runtime.h>
#include <stdint.h>

namespace {
constexpr int kNodes = 50000;
constexpr int kEdges = 800000;
constexpr int kHid   = 128;

// workspace layout (bytes, 256-aligned)
constexpr size_t oCounts    = 0;        // 50000*4 = 200000
constexpr size_t oRowStart  = 200704;   // 200000
constexpr size_t oCursor    = 401408;   // 200000
constexpr size_t oBlockSums = 602112;   // 196*4
constexpr size_t oPacked    = 603136;   // 800000*4 = 3200000
constexpr size_t oDegW      = 3803136;  // 50000*4*4 = 800000
constexpr size_t oMsg       = 4603392;  // 50000*128*4 = 25600000
constexpr size_t kWsNeeded  = oMsg + (size_t)kNodes * kHid * 4;

constexpr int kScanBlocks = (kNodes + 255) / 256;  // 196
}

__global__ __launch_bounds__(256) void count_kernel(const int* __restrict__ edges,
                                                    int* __restrict__ counts) {
  int e = blockIdx.x * 256 + threadIdx.x;
  if (e < kEdges) atomicAdd(&counts[edges[e * 3 + 2]], 1);
}

__global__ __launch_bounds__(256) void scan1_kernel(const int* __restrict__ counts,
                                                    int* __restrict__ row_start,
                                                    int* __restrict__ blocksums) {
  __shared__ int sd[256];
  const int t = threadIdx.x;
  const int i = blockIdx.x * 256 + t;
  int v = (i < kNodes) ? counts[i] : 0;
  sd[t] = v;
  __syncthreads();
  for (int off = 1; off < 256; off <<= 1) {
    int x = (t >= off) ? sd[t - off] : 0;
    __syncthreads();
    sd[t] += x;
    __syncthreads();
  }
  if (i < kNodes) row_start[i] = sd[t] - v;  // exclusive within block
  if (t == 255) blocksums[blockIdx.x] = sd[255];
}

__global__ __launch_bounds__(256) void scan2_kernel(int* __restrict__ blocksums) {
  __shared__ int sd[256];
  const int t = threadIdx.x;
  int v = (t < kScanBlocks) ? blocksums[t] : 0;
  sd[t] = v;
  __syncthreads();
  for (int off = 1; off < 256; off <<= 1) {
    int x = (t >= off) ? sd[t - off] : 0;
    __syncthreads();
    sd[t] += x;
    __syncthreads();
  }
  if (t < kScanBlocks) blocksums[t] = sd[t] - v;  // exclusive block offsets
}

__global__ __launch_bounds__(256) void scan3_kernel(int* __restrict__ row_start,
                                                    const int* __restrict__ blocksums,
                                                    int* __restrict__ cursor) {
  const int i = blockIdx.x * 256 + threadIdx.x;
  if (i < kNodes) {
    int r = row_start[i] + blocksums[blockIdx.x];
    row_start[i] = r;
    cursor[i] = r;
  }
}

__global__ __launch_bounds__(256) void fill_kernel(const int* __restrict__ edges,
                                                   int* __restrict__ cursor,
                                                   unsigned* __restrict__ packed) {
  int e = blockIdx.x * 256 + threadIdx.x;
  if (e < kEdges) {
    const int et  = edges[e * 3 + 0];
    const int src = edges[e * 3 + 1];
    const int tgt = edges[e * 3 + 2];
    const int pos = atomicAdd(&cursor[tgt], 1);
    packed[pos] = (unsigned)src | ((unsigned)et << 18);
  }
}

// One block = 32 nodes. Phase 1: CSR gather of h[src] into per-type LDS
// accumulators S[node][4*128] (64 KB, exactly the static limit). Phase 2:
// msg = S @ W (+ deg @ type_bias), register-tiled 4 nodes x 4 cols/thread.
__global__ __launch_bounds__(256, 2) void message_kernel(
    const float* __restrict__ hin,
    const unsigned* __restrict__ packed,
    const int* __restrict__ row_start,
    const int* __restrict__ counts,
    const float* __restrict__ W,     // [4][128][128]
    const float* __restrict__ TB,    // [4][128]
    int* __restrict__ degW,          // [kNodes][4]
    float* __restrict__ msg) {
  __shared__ float S[32 * 512];  // 64 KB
  const int tid = threadIdx.x;

  // ---- phase 1: edge aggregation (2 groups of 128 threads, 16 nodes each)
  {
    const int g = tid >> 7;
    const int j = tid & 127;
    for (int i = 0; i < 16; ++i) {
      const int nl = g * 16 + i;
      const int v = blockIdx.x * 32 + nl;
      if (v >= kNodes) break;
      const int s0  = row_start[v];
      const int cnt = counts[v];
      float a0 = 0.f, a1 = 0.f, a2 = 0.f, a3 = 0.f;
      int d0 = 0, d1 = 0, d2 = 0, d3 = 0;
      for (int e = 0; e < cnt; ++e) {
        const unsigned p = packed[s0 + e];
        const int src = (int)(p & 0x3FFFFu);
        const int t = (int)(p >> 18);
        const float val = hin[(size_t)src * kHid + j];
        a0 += (t == 0) ? val : 0.f;
        a1 += (t == 1) ? val : 0.f;
        a2 += (t == 2) ? val : 0.f;
        a3 += (t == 3) ? val : 0.f;
        d0 += (t == 0); d1 += (t == 1); d2 += (t == 2); d3 += (t == 3);
      }
      float* Sn = &S[nl * 512];
      Sn[j] = a0; Sn[128 + j] = a1; Sn[256 + j] = a2; Sn[384 + j] = a3;
      if (j == 0) {
        *(int4*)&degW[(size_t)v * 4] = make_int4(d0, d1, d2, d3);
      }
    }
  }
  __syncthreads();

  // ---- phase 2: msg = S @ W  (K = 512)
  const int lane = tid & 31;
  const int jj = lane * 4;        // output column base
  const int ng = tid >> 5;        // 8 node-groups
  const int n0 = ng * 4;
  float acc[4][4];
#pragma unroll
  for (int n = 0; n < 4; ++n)
#pragma unroll
    for (int c = 0; c < 4; ++c) acc[n][c] = 0.f;

  const float4* __restrict__ W4 = (const float4*)W;
  for (int tk = 0; tk < 512; tk += 4) {
    const float4 w0 = W4[(size_t)(tk + 0) * 32 + lane];
    const float4 w1 = W4[(size_t)(tk + 1) * 32 + lane];
    const float4 w2 = W4[(size_t)(tk + 2) * 32 + lane];
    const float4 w3 = W4[(size_t)(tk + 3) * 32 + lane];
#pragma unroll
    for (int n = 0; n < 4; ++n) {
      const float4 s = *(const float4*)&S[(n0 + n) * 512 + tk];
      acc[n][0] += s.x * w0.x + s.y * w1.x + s.z * w2.x + s.w * w3.x;
      acc[n][1] += s.x * w0.y + s.y * w1.y + s.z * w2.y + s.w * w3.y;
      acc[n][2] += s.x * w0.z + s.y * w1.z + s.z * w2.z + s.w * w3.z;
      acc[n][3] += s.x * w0.w + s.y * w1.w + s.z * w2.w + s.w * w3.w;
    }
  }

  const float4 B0 = *(const float4*)&TB[0 * 128 + jj];
  const float4 B1 = *(const float4*)&TB[1 * 128 + jj];
  const float4 B2 = *(const float4*)&TB[2 * 128 + jj];
  const float4 B3 = *(const float4*)&TB[3 * 128 + jj];
#pragma unroll
  for (int n = 0; n < 4; ++n) {
    const int v = blockIdx.x * 32 + n0 + n;
    if (v < kNodes) {
      const int4 dg = *(const int4*)&degW[(size_t)v * 4];
      float4 o;
      o.x = acc[n][0] + dg.x * B0.x + dg.y * B1.x + dg.z * B2.x + dg.w * B3.x;
      o.y = acc[n][1] + dg.x * B0.y + dg.y * B1.y + dg.z * B2.y + dg.w * B3.y;
      o.z = acc[n][2] + dg.x * B0.z + dg.y * B1.z + dg.z * B2.z + dg.w * B3.z;
      o.w = acc[n][3] + dg.x * B0.w + dg.y * B1.w + dg.z * B2.w + dg.w * B3.w;
      *(float4*)&msg[(size_t)v * kHid + jj] = o;
    }
  }
}

__device__ __forceinline__ float sigf(float x) {
  return 1.f / (1.f + __expf(-x));
}
__device__ __forceinline__ float tanh_fast(float x) {
  x = fminf(fmaxf(x, -15.f), 15.f);
  const float e2 = __expf(2.f * x);
  return (e2 - 1.f) / (e2 + 1.f);
}

// One block = 16 nodes. Computes GRU(msg, h) -> hout. Safe for hin == hout
// (each block stages its own region in LDS before writing).
__global__ __launch_bounds__(256) void gru_kernel(
    const float* __restrict__ msg,
    const float* __restrict__ hin,
    const float* __restrict__ K,    // [128][384]  cols: z | r | h
    const float* __restrict__ R,    // [128][384]
    const float* __restrict__ gb,   // [2][384]
    float* __restrict__ hout) {
  __shared__ float M[16 * 128];
  __shared__ float H[16 * 128];
  const int tid = threadIdx.x;
  const size_t base = (size_t)blockIdx.x * (16 * 128);
  {
    const float4* m4 = (const float4*)(msg + base);
    const float4* h4 = (const float4*)(hin + base);
    float4* Ms = (float4*)M;
    float4* Hs = (float4*)H;
    Ms[tid] = m4[tid];
    Ms[tid + 256] = m4[tid + 256];
    Hs[tid] = h4[tid];
    Hs[tid + 256] = h4[tid + 256];
  }
  __syncthreads();

  const int jg = tid & 63;
  const int j = jg * 2;
  const int nb = tid >> 6;
  const int nf = nb * 4;

  float aXZ[4][2] = {}, aXR[4][2] = {}, aXH[4][2] = {};
  float aRZ[4][2] = {}, aRR[4][2] = {}, aRH[4][2] = {};
  const float2* __restrict__ K2 = (const float2*)K;
  const float2* __restrict__ R2 = (const float2*)R;

  for (int k = 0; k < 128; k += 4) {
    float4 m4[4], h4[4];
#pragma unroll
    for (int n = 0; n < 4; ++n) {
      m4[n] = *(const float4*)&M[(nf + n) * 128 + k];
      h4[n] = *(const float4*)&H[(nf + n) * 128 + k];
    }
#pragma unroll
    for (int kk = 0; kk < 4; ++kk) {
      const int kr = (k + kk) * 192;
      const float2 wkz = K2[kr + jg];
      const float2 wkr = K2[kr + 64 + jg];
      const float2 wkh = K2[kr + 128 + jg];
      const float2 wrz = R2[kr + jg];
      const float2 wrr = R2[kr + 64 + jg];
      const float2 wrh = R2[kr + 128 + jg];
#pragma unroll
      for (int n = 0; n < 4; ++n) {
        const float m = (kk == 0) ? m4[n].x : (kk == 1) ? m4[n].y : (kk == 2) ? m4[n].z : m4[n].w;
        const float h = (kk == 0) ? h4[n].x : (kk == 1) ? h4[n].y : (kk == 2) ? h4[n].z : h4[n].w;
        aXZ[n][0] += m * wkz.x; aXZ[n][1] += m * wkz.y;
        aXR[n][0] += m * wkr.x; aXR[n][1] += m * wkr.y;
        aXH[n][0] += m * wkh.x; aXH[n][1] += m * wkh.y;
        aRZ[n][0] += h * wrz.x; aRZ[n][1] += h * wrz.y;
        aRR[n][0] += h * wrr.x; aRR[n][1] += h * wrr.y;
        aRH[n][0] += h * wrh.x; aRH[n][1] += h * wrh.y;
      }
    }
  }

  const float b0z[2] = {gb[j], gb[j + 1]};
  const float b0r[2] = {gb[128 + j], gb[128 + j + 1]};
  const float b0h[2] = {gb[256 + j], gb[256 + j + 1]};
  const float b1z[2] = {gb[384 + j], gb[384 + j + 1]};
  const float b1r[2] = {gb[512 + j], gb[512 + j + 1]};
  const float b1h[2] = {gb[640 + j], gb[640 + j + 1]};

#pragma unroll
  for (int n = 0; n < 4; ++n) {
    float o[2];
#pragma unroll
    for (int c = 0; c < 2; ++c) {
      const float xz = aXZ[n][c] + b0z[c];
      const float xr = aXR[n][c] + b0r[c];
      const float xh = aXH[n][c] + b0h[c];
      const float rz = aRZ[n][c] + b1z[c];
      const float rr = aRR[n][c] + b1r[c];
      const float rh = aRH[n][c] + b1h[c];
      const float z = sigf(xz + rz);
      const float r = sigf(xr + rr);
      const float hh = tanh_fast(xh + r * rh);
      const float hp = H[(nf + n) * 128 + j + c];
      o[c] = z * hp + (1.f - z) * hh;
    }
    *(float2*)&hout[base + (size_t)(nf + n) * 128 + j] = make_float2(o[0], o[1]);
  }
}

extern "C" void kernel_launch(void* const* d_in, const int* in_sizes, int n_in,
                              void* d_out, int out_size, void* d_ws, size_t ws_size,
                              hipStream_t stream) {
  const float* states = (const float*)d_in[0];
  const int*   edges  = (const int*)d_in[1];
  const float* W      = (const float*)d_in[2];
  const float* TB     = (const float*)d_in[3];
  const float* K      = (const float*)d_in[4];
  const float* R      = (const float*)d_in[5];
  const float* gb     = (const float*)d_in[6];
  float* out = (float*)d_out;

  if (ws_size < kWsNeeded) return;  // memory-safety guard

  char* ws = (char*)d_ws;
  int*      counts    = (int*)(ws + oCounts);
  int*      row_start = (int*)(ws + oRowStart);
  int*      cursor    = (int*)(ws + oCursor);
  int*      blocksums = (int*)(ws + oBlockSums);
  unsigned* packed    = (unsigned*)(ws + oPacked);
  int*      degW      = (int*)(ws + oDegW);
  float*    msg       = (float*)(ws + oMsg);

  // --- build CSR by target (identical every call; graph-capture safe)
  hipMemsetAsync(counts, 0, kNodes * sizeof(int), stream);
  count_kernel<<<kEdges / 256, 256, 0, stream>>>(edges, counts);
  scan1_kernel<<<kScanBlocks, 256, 0, stream>>>(counts, row_start, blocksums);
  scan2_kernel<<<1, 256, 0, stream>>>(blocksums);
  scan3_kernel<<<kScanBlocks, 256, 0, stream>>>(row_start, blocksums, cursor);
  fill_kernel<<<kEdges / 256, 256, 0, stream>>>(edges, cursor, packed);

  const int msg_blocks = (kNodes + 31) / 32;  // 1563
  const int gru_blocks = kNodes / 16;         // 3125 (exact)

  // --- step 1
  message_kernel<<<msg_blocks, 256, 0, stream>>>(states, packed, row_start, counts,
                                                 W, TB, degW, msg);
  gru_kernel<<<gru_blocks, 256, 0, stream>>>(msg, states, K, R, gb, out);
  // --- step 2 (in-place on d_out; block-disjoint, LDS-staged)
  message_kernel<<<msg_blocks, 256, 0, stream>>>(out, packed, row_start, counts,
                                                 W, TB, degW, msg);
  gru_kernel<<<gru_blocks, 256, 0, stream>>>(msg, out, K, R, gb, out);
}

// Round 2
// 1100.787 us; speedup vs baseline: 1.8861x; 1.8861x over previous
//
#include <hip/hip_runtime.h>
#include <stdint.h>

namespace {
constexpr int kNodes = 50000;
constexpr int kEdges = 800000;
constexpr int kHid   = 128;

// workspace layout (bytes, 256-aligned)
constexpr size_t oCounts    = 0;         // 50000*4 = 200000
constexpr size_t oDegT      = 200704;    // 50000*4*4 = 800000
constexpr size_t oRowStart  = 1000704;   // 200000
constexpr size_t oCursor    = 1200896;   // 200000
constexpr size_t oBlockSums = 1401088;   // 196*4
constexpr size_t oPacked    = 1402112;   // 800000*4 = 3200000
constexpr size_t oMsg       = 4602112;   // 50000*128*4 = 25600000
constexpr size_t oY         = 30202112;  // 50000*512*2 = 51200000 (bf16)
constexpr size_t kWsNeeded  = oY + (size_t)kNodes * 512 * 2;   // ~81.4 MB
constexpr size_t kWsFallback = oMsg + (size_t)kNodes * kHid * 4; // ~30.2 MB

constexpr int kScanBlocks = (kNodes + 255) / 256;  // 196
}

__device__ __forceinline__ uint32_t f2bf(float x) {
  uint32_t u = __float_as_uint(x);
  return (u + 0x7FFFu + ((u >> 16) & 1u)) >> 16;
}

// ---------------- CSR build ----------------

__global__ __launch_bounds__(256) void count_kernel(const int* __restrict__ edges,
                                                    int* __restrict__ counts,
                                                    int* __restrict__ degT) {
  int e = blockIdx.x * 256 + threadIdx.x;
  if (e < kEdges) {
    const int et  = edges[e * 3 + 0];
    const int tgt = edges[e * 3 + 2];
    atomicAdd(&counts[tgt], 1);
    atomicAdd(&degT[tgt * 4 + et], 1);
  }
}

__global__ __launch_bounds__(256) void scan1_kernel(const int* __restrict__ counts,
                                                    int* __restrict__ row_start,
                                                    int* __restrict__ blocksums) {
  __shared__ int sd[256];
  const int t = threadIdx.x;
  const int i = blockIdx.x * 256 + t;
  int v = (i < kNodes) ? counts[i] : 0;
  sd[t] = v;
  __syncthreads();
  for (int off = 1; off < 256; off <<= 1) {
    int x = (t >= off) ? sd[t - off] : 0;
    __syncthreads();
    sd[t] += x;
    __syncthreads();
  }
  if (i < kNodes) row_start[i] = sd[t] - v;
  if (t == 255) blocksums[blockIdx.x] = sd[255];
}

__global__ __launch_bounds__(256) void scan2_kernel(int* __restrict__ blocksums) {
  __shared__ int sd[256];
  const int t = threadIdx.x;
  int v = (t < kScanBlocks) ? blocksums[t] : 0;
  sd[t] = v;
  __syncthreads();
  for (int off = 1; off < 256; off <<= 1) {
    int x = (t >= off) ? sd[t - off] : 0;
    __syncthreads();
    sd[t] += x;
    __syncthreads();
  }
  if (t < kScanBlocks) blocksums[t] = sd[t] - v;
}

__global__ __launch_bounds__(256) void scan3_kernel(int* __restrict__ row_start,
                                                    const int* __restrict__ blocksums,
                                                    int* __restrict__ cursor) {
  const int i = blockIdx.x * 256 + threadIdx.x;
  if (i < kNodes) {
    int r = row_start[i] + blocksums[blockIdx.x];
    row_start[i] = r;
    cursor[i] = r;
  }
}

__global__ __launch_bounds__(256) void fill_kernel(const int* __restrict__ edges,
                                                   int* __restrict__ cursor,
                                                   unsigned* __restrict__ packed) {
  int e = blockIdx.x * 256 + threadIdx.x;
  if (e < kEdges) {
    const int et  = edges[e * 3 + 0];
    const int src = edges[e * 3 + 1];
    const int tgt = edges[e * 3 + 2];
    const int pos = atomicAdd(&cursor[tgt], 1);
    packed[pos] = (unsigned)(src * 4 + et);  // row index into y[(src,t)][128]
  }
}

// ---------------- transform: y[u][t*128+c] = h[u] @ W_t ----------------
// grid = 1563 node-tiles x 4 type(col)-tiles; 32 nodes x 128 cols per block.
__global__ __launch_bounds__(256) void transform_kernel(
    const float* __restrict__ h,     // [N][128]
    const float* __restrict__ W,     // [4][128][128]
    uint16_t* __restrict__ y16) {    // [N][512] bf16
  __shared__ float Sh[32 * 128];  // 16 KB
  const int tid = threadIdx.x;
  const int t  = blockIdx.x & 3;
  const int node0 = (blockIdx.x >> 2) * 32;
  const int nvalid = min(32, kNodes - node0);

  {
    const float4* hsrc = (const float4*)(h + (size_t)node0 * kHid);
    float4* sdst = (float4*)Sh;
#pragma unroll
    for (int i = 0; i < 4; ++i) {
      const int idx = tid + i * 256;           // 0..1023 float4s
      const int nl = idx >> 5;
      sdst[idx] = (nl < nvalid) ? hsrc[idx] : make_float4(0.f, 0.f, 0.f, 0.f);
    }
  }
  __syncthreads();

  const int lane = tid & 31;         // output col group: cols lane*4..+3
  const int n0 = (tid >> 5) * 4;     // 4 nodes per thread
  float acc[4][4] = {};
  const float4* __restrict__ W4 = (const float4*)(W + (size_t)t * 16384);

  for (int k = 0; k < 128; k += 4) {
    const float4 w0 = W4[(k + 0) * 32 + lane];
    const float4 w1 = W4[(k + 1) * 32 + lane];
    const float4 w2 = W4[(k + 2) * 32 + lane];
    const float4 w3 = W4[(k + 3) * 32 + lane];
#pragma unroll
    for (int n = 0; n < 4; ++n) {
      const float4 s = *(const float4*)&Sh[(n0 + n) * kHid + k];
      acc[n][0] += s.x * w0.x + s.y * w1.x + s.z * w2.x + s.w * w3.x;
      acc[n][1] += s.x * w0.y + s.y * w1.y + s.z * w2.y + s.w * w3.y;
      acc[n][2] += s.x * w0.z + s.y * w1.z + s.z * w2.z + s.w * w3.z;
      acc[n][3] += s.x * w0.w + s.y * w1.w + s.z * w2.w + s.w * w3.w;
    }
  }

#pragma unroll
  for (int n = 0; n < 4; ++n) {
    const int node = node0 + n0 + n;
    if (node < kNodes) {
      const uint32_t lo = f2bf(acc[n][0]) | (f2bf(acc[n][1]) << 16);
      const uint32_t hi = f2bf(acc[n][2]) | (f2bf(acc[n][3]) << 16);
      *(uint2*)&y16[(size_t)node * 512 + t * 128 + lane * 4] = make_uint2(lo, hi);
    }
  }
}

// ---------------- gather: msg[v] = sum_e y[src_e*4+t_e] + deg.b ----------------
// one wave per node, lane handles cols 2*lane, 2*lane+1. No LDS.
__global__ __launch_bounds__(256) void gather_kernel(
    const uint32_t* __restrict__ y2,      // y as uint32 pairs: [row][64]
    const uint32_t* __restrict__ packed,
    const int* __restrict__ row_start,
    const int* __restrict__ counts,
    const int* __restrict__ degT,
    const float* __restrict__ TB,         // [4][128]
    float* __restrict__ msg) {
  const int tid = threadIdx.x;
  const int lane = tid & 63;
  const int v = blockIdx.x * 4 + (tid >> 6);
  const int s0 = row_start[v];
  const int cnt = counts[v];
  float a0 = 0.f, a1 = 0.f;
  int e = 0;
  for (; e + 4 <= cnt; e += 4) {
    const uint32_t p0 = packed[s0 + e + 0];
    const uint32_t p1 = packed[s0 + e + 1];
    const uint32_t p2 = packed[s0 + e + 2];
    const uint32_t p3 = packed[s0 + e + 3];
    const uint32_t u0 = y2[(size_t)p0 * 64 + lane];
    const uint32_t u1 = y2[(size_t)p1 * 64 + lane];
    const uint32_t u2 = y2[(size_t)p2 * 64 + lane];
    const uint32_t u3 = y2[(size_t)p3 * 64 + lane];
    a0 += __uint_as_float(u0 << 16) + __uint_as_float(u1 << 16) +
          __uint_as_float(u2 << 16) + __uint_as_float(u3 << 16);
    a1 += __uint_as_float(u0 & 0xFFFF0000u) + __uint_as_float(u1 & 0xFFFF0000u) +
          __uint_as_float(u2 & 0xFFFF0000u) + __uint_as_float(u3 & 0xFFFF0000u);
  }
  for (; e < cnt; ++e) {
    const uint32_t p = packed[s0 + e];
    const uint32_t u = y2[(size_t)p * 64 + lane];
    a0 += __uint_as_float(u << 16);
    a1 += __uint_as_float(u & 0xFFFF0000u);
  }
  const int4 dg = *(const int4*)&degT[v * 4];
  const float2 b0 = *(const float2*)&TB[0 * 128 + lane * 2];
  const float2 b1 = *(const float2*)&TB[1 * 128 + lane * 2];
  const float2 b2 = *(const float2*)&TB[2 * 128 + lane * 2];
  const float2 b3 = *(const float2*)&TB[3 * 128 + lane * 2];
  a0 += dg.x * b0.x + dg.y * b1.x + dg.z * b2.x + dg.w * b3.x;
  a1 += dg.x * b0.y + dg.y * b1.y + dg.z * b2.y + dg.w * b3.y;
  *(float2*)&msg[(size_t)v * kHid + lane * 2] = make_float2(a0, a1);
}

// ---------------- fallback message kernel (round-1 proven path) ----------------
__global__ __launch_bounds__(256, 2) void message_fb_kernel(
    const float* __restrict__ hin,
    const unsigned* __restrict__ packed,
    const int* __restrict__ row_start,
    const int* __restrict__ counts,
    const float* __restrict__ W,
    const float* __restrict__ TB,
    const int* __restrict__ degT,
    float* __restrict__ msg) {
  __shared__ float S[32 * 512];  // 64 KB
  const int tid = threadIdx.x;
  {
    const int g = tid >> 7;
    const int j = tid & 127;
    for (int i = 0; i < 16; ++i) {
      const int nl = g * 16 + i;
      const int v = blockIdx.x * 32 + nl;
      if (v >= kNodes) break;
      const int s0  = row_start[v];
      const int cnt = counts[v];
      float a0 = 0.f, a1 = 0.f, a2 = 0.f, a3 = 0.f;
      for (int e = 0; e < cnt; ++e) {
        const unsigned p = packed[s0 + e];
        const int src = (int)(p >> 2);
        const int t = (int)(p & 3u);
        const float val = hin[(size_t)src * kHid + j];
        a0 += (t == 0) ? val : 0.f;
        a1 += (t == 1) ? val : 0.f;
        a2 += (t == 2) ? val : 0.f;
        a3 += (t == 3) ? val : 0.f;
      }
      float* Sn = &S[nl * 512];
      Sn[j] = a0; Sn[128 + j] = a1; Sn[256 + j] = a2; Sn[384 + j] = a3;
    }
  }
  __syncthreads();

  const int lane = tid & 31;
  const int jj = lane * 4;
  const int n0 = (tid >> 5) * 4;
  float acc[4][4] = {};
  const float4* __restrict__ W4 = (const float4*)W;
  for (int tk = 0; tk < 512; tk += 4) {
    const float4 w0 = W4[(size_t)(tk + 0) * 32 + lane];
    const float4 w1 = W4[(size_t)(tk + 1) * 32 + lane];
    const float4 w2 = W4[(size_t)(tk + 2) * 32 + lane];
    const float4 w3 = W4[(size_t)(tk + 3) * 32 + lane];
#pragma unroll
    for (int n = 0; n < 4; ++n) {
      const float4 s = *(const float4*)&S[(n0 + n) * 512 + tk];
      acc[n][0] += s.x * w0.x + s.y * w1.x + s.z * w2.x + s.w * w3.x;
      acc[n][1] += s.x * w0.y + s.y * w1.y + s.z * w2.y + s.w * w3.y;
      acc[n][2] += s.x * w0.z + s.y * w1.z + s.z * w2.z + s.w * w3.z;
      acc[n][3] += s.x * w0.w + s.y * w1.w + s.z * w2.w + s.w * w3.w;
    }
  }
  const float4 B0 = *(const float4*)&TB[0 * 128 + jj];
  const float4 B1 = *(const float4*)&TB[1 * 128 + jj];
  const float4 B2 = *(const float4*)&TB[2 * 128 + jj];
  const float4 B3 = *(const float4*)&TB[3 * 128 + jj];
#pragma unroll
  for (int n = 0; n < 4; ++n) {
    const int v = blockIdx.x * 32 + n0 + n;
    if (v < kNodes) {
      const int4 dg = *(const int4*)&degT[(size_t)v * 4];
      float4 o;
      o.x = acc[n][0] + dg.x * B0.x + dg.y * B1.x + dg.z * B2.x + dg.w * B3.x;
      o.y = acc[n][1] + dg.x * B0.y + dg.y * B1.y + dg.z * B2.y + dg.w * B3.y;
      o.z = acc[n][2] + dg.x * B0.z + dg.y * B1.z + dg.z * B2.z + dg.w * B3.z;
      o.w = acc[n][3] + dg.x * B0.w + dg.y * B1.w + dg.z * B2.w + dg.w * B3.w;
      *(float4*)&msg[(size_t)v * kHid + jj] = o;
    }
  }
}

// ---------------- GRU ----------------

__device__ __forceinline__ float sigf(float x) {
  return 1.f / (1.f + __expf(-x));
}
__device__ __forceinline__ float tanh_fast(float x) {
  x = fminf(fmaxf(x, -15.f), 15.f);
  const float e2 = __expf(2.f * x);
  return (e2 - 1.f) / (e2 + 1.f);
}

__global__ __launch_bounds__(256) void gru_kernel(
    const float* __restrict__ msg,
    const float* __restrict__ hin,
    const float* __restrict__ K,    // [128][384]
    const float* __restrict__ R,    // [128][384]
    const float* __restrict__ gb,   // [2][384]
    float* __restrict__ hout) {
  __shared__ float M[16 * 128];
  __shared__ float H[16 * 128];
  const int tid = threadIdx.x;
  const size_t base = (size_t)blockIdx.x * (16 * 128);
  {
    const float4* m4 = (const float4*)(msg + base);
    const float4* h4 = (const float4*)(hin + base);
    float4* Ms = (float4*)M;
    float4* Hs = (float4*)H;
    Ms[tid] = m4[tid];
    Ms[tid + 256] = m4[tid + 256];
    Hs[tid] = h4[tid];
    Hs[tid + 256] = h4[tid + 256];
  }
  __syncthreads();

  const int jg = tid & 63;
  const int j = jg * 2;
  const int nf = (tid >> 6) * 4;

  float aXZ[4][2] = {}, aXR[4][2] = {}, aXH[4][2] = {};
  float aRZ[4][2] = {}, aRR[4][2] = {}, aRH[4][2] = {};
  const float2* __restrict__ K2 = (const float2*)K;
  const float2* __restrict__ R2 = (const float2*)R;

  for (int k = 0; k < 128; k += 4) {
    float4 m4[4], h4[4];
#pragma unroll
    for (int n = 0; n < 4; ++n) {
      m4[n] = *(const float4*)&M[(nf + n) * 128 + k];
      h4[n] = *(const float4*)&H[(nf + n) * 128 + k];
    }
#pragma unroll
    for (int kk = 0; kk < 4; ++kk) {
      const int kr = (k + kk) * 192;
      const float2 wkz = K2[kr + jg];
      const float2 wkr = K2[kr + 64 + jg];
      const float2 wkh = K2[kr + 128 + jg];
      const float2 wrz = R2[kr + jg];
      const float2 wrr = R2[kr + 64 + jg];
      const float2 wrh = R2[kr + 128 + jg];
#pragma unroll
      for (int n = 0; n < 4; ++n) {
        const float m = (kk == 0) ? m4[n].x : (kk == 1) ? m4[n].y : (kk == 2) ? m4[n].z : m4[n].w;
        const float h = (kk == 0) ? h4[n].x : (kk == 1) ? h4[n].y : (kk == 2) ? h4[n].z : h4[n].w;
        aXZ[n][0] += m * wkz.x; aXZ[n][1] += m * wkz.y;
        aXR[n][0] += m * wkr.x; aXR[n][1] += m * wkr.y;
        aXH[n][0] += m * wkh.x; aXH[n][1] += m * wkh.y;
        aRZ[n][0] += h * wrz.x; aRZ[n][1] += h * wrz.y;
        aRR[n][0] += h * wrr.x; aRR[n][1] += h * wrr.y;
        aRH[n][0] += h * wrh.x; aRH[n][1] += h * wrh.y;
      }
    }
  }

  const float b0z[2] = {gb[j], gb[j + 1]};
  const float b0r[2] = {gb[128 + j], gb[128 + j + 1]};
  const float b0h[2] = {gb[256 + j], gb[256 + j + 1]};
  const float b1z[2] = {gb[384 + j], gb[384 + j + 1]};
  const float b1r[2] = {gb[512 + j], gb[512 + j + 1]};
  const float b1h[2] = {gb[640 + j], gb[640 + j + 1]};

#pragma unroll
  for (int n = 0; n < 4; ++n) {
    float o[2];
#pragma unroll
    for (int c = 0; c < 2; ++c) {
      const float xz = aXZ[n][c] + b0z[c];
      const float xr = aXR[n][c] + b0r[c];
      const float xh = aXH[n][c] + b0h[c];
      const float rz = aRZ[n][c] + b1z[c];
      const float rr = aRR[n][c] + b1r[c];
      const float rh = aRH[n][c] + b1h[c];
      const float z = sigf(xz + rz);
      const float r = sigf(xr + rr);
      const float hh = tanh_fast(xh + r * rh);
      const float hp = H[(nf + n) * 128 + j + c];
      o[c] = z * hp + (1.f - z) * hh;
    }
    *(float2*)&hout[base + (size_t)(nf + n) * 128 + j] = make_float2(o[0], o[1]);
  }
}

extern "C" void kernel_launch(void* const* d_in, const int* in_sizes, int n_in,
                              void* d_out, int out_size, void* d_ws, size_t ws_size,
                              hipStream_t stream) {
  const float* states = (const float*)d_in[0];
  const int*   edges  = (const int*)d_in[1];
  const float* W      = (const float*)d_in[2];
  const float* TB     = (const float*)d_in[3];
  const float* K      = (const float*)d_in[4];
  const float* R      = (const float*)d_in[5];
  const float* gb     = (const float*)d_in[6];
  float* out = (float*)d_out;

  if (ws_size < kWsFallback) return;  // cannot run at all

  char* ws = (char*)d_ws;
  int*      counts    = (int*)(ws + oCounts);
  int*      degT      = (int*)(ws + oDegT);
  int*      row_start = (int*)(ws + oRowStart);
  int*      cursor    = (int*)(ws + oCursor);
  int*      blocksums = (int*)(ws + oBlockSums);
  unsigned* packed    = (unsigned*)(ws + oPacked);
  float*    msg       = (float*)(ws + oMsg);
  uint16_t* y16       = (uint16_t*)(ws + oY);
  uint32_t* y2        = (uint32_t*)(ws + oY);

  // --- build CSR by target + per-type in-degrees
  hipMemsetAsync(counts, 0, oRowStart - oCounts, stream);  // counts + degT
  count_kernel<<<kEdges / 256, 256, 0, stream>>>(edges, counts, degT);
  scan1_kernel<<<kScanBlocks, 256, 0, stream>>>(counts, row_start, blocksums);
  scan2_kernel<<<1, 256, 0, stream>>>(blocksums);
  scan3_kernel<<<kScanBlocks, 256, 0, stream>>>(row_start, blocksums, cursor);
  fill_kernel<<<kEdges / 256, 256, 0, stream>>>(edges, cursor, packed);

  const int gru_blocks = kNodes / 16;  // 3125

  if (ws_size >= kWsNeeded) {
    const int tf_blocks = ((kNodes + 31) / 32) * 4;  // 6252
    const int ga_blocks = kNodes / 4;                // 12500
    // step 1
    transform_kernel<<<tf_blocks, 256, 0, stream>>>(states, W, y16);
    gather_kernel<<<ga_blocks, 256, 0, stream>>>(y2, packed, row_start, counts,
                                                 degT, TB, msg);
    gru_kernel<<<gru_blocks, 256, 0, stream>>>(msg, states, K, R, gb, out);
    // step 2
    transform_kernel<<<tf_blocks, 256, 0, stream>>>(out, W, y16);
    gather_kernel<<<ga_blocks, 256, 0, stream>>>(y2, packed, row_start, counts,
                                                 degT, TB, msg);
    gru_kernel<<<gru_blocks, 256, 0, stream>>>(msg, out, K, R, gb, out);
  } else {
    const int msg_blocks = (kNodes + 31) / 32;  // 1563
    message_fb_kernel<<<msg_blocks, 256, 0, stream>>>(states, packed, row_start,
                                                      counts, W, TB, degT, msg);
    gru_kernel<<<gru_blocks, 256, 0, stream>>>(msg, states, K, R, gb, out);
    message_fb_kernel<<<msg_blocks, 256, 0, stream>>>(out, packed, row_start,
                                                      counts, W, TB, degT, msg);
    gru_kernel<<<gru_blocks, 256, 0, stream>>>(msg, out, K, R, gb, out);
  }
}

// Round 3
// 925.404 us; speedup vs baseline: 2.2436x; 1.1895x over previous
//
#include <hip/hip_runtime.h>
#include <stdint.h>

namespace {
constexpr int kNodes = 50000;
constexpr int kEdges = 800000;
constexpr int kHid   = 128;

// workspace layout (bytes, 256-aligned)
constexpr size_t oCounts    = 0;         // 50000*4 = 200000
constexpr size_t oDegT      = 200704;    // 50000*4*4 = 800000
constexpr size_t oRowStart  = 1000704;   // 200000
constexpr size_t oCursor    = 1200896;   // 200000
constexpr size_t oBlockSums = 1401088;   // 196*4
constexpr size_t oPacked    = 1402112;   // 800000*4 = 3200000
constexpr size_t oMsg       = 4602112;   // 50000*128*4 = 25600000
constexpr size_t oY         = 30202112;  // 50000*512*2 = 51200000 (bf16)
constexpr size_t kWsNeeded  = oY + (size_t)kNodes * 512 * 2;   // ~81.4 MB
constexpr size_t kWsFallback = oMsg + (size_t)kNodes * kHid * 4; // ~30.2 MB

constexpr int kScanBlocks = (kNodes + 255) / 256;  // 196
}

__device__ __forceinline__ uint32_t f2bf(float x) {
  uint32_t u = __float_as_uint(x);
  return (u + 0x7FFFu + ((u >> 16) & 1u)) >> 16;
}

// ---------------- CSR build ----------------

__global__ __launch_bounds__(256) void count_kernel(const int* __restrict__ edges,
                                                    int* __restrict__ counts,
                                                    int* __restrict__ degT) {
  int e = blockIdx.x * 256 + threadIdx.x;
  if (e < kEdges) {
    const int et  = edges[e * 3 + 0];
    const int tgt = edges[e * 3 + 2];
    atomicAdd(&counts[tgt], 1);
    atomicAdd(&degT[tgt * 4 + et], 1);
  }
}

__global__ __launch_bounds__(256) void scan1_kernel(const int* __restrict__ counts,
                                                    int* __restrict__ row_start,
                                                    int* __restrict__ blocksums) {
  __shared__ int sd[256];
  const int t = threadIdx.x;
  const int i = blockIdx.x * 256 + t;
  int v = (i < kNodes) ? counts[i] : 0;
  sd[t] = v;
  __syncthreads();
  for (int off = 1; off < 256; off <<= 1) {
    int x = (t >= off) ? sd[t - off] : 0;
    __syncthreads();
    sd[t] += x;
    __syncthreads();
  }
  if (i < kNodes) row_start[i] = sd[t] - v;
  if (t == 255) blocksums[blockIdx.x] = sd[255];
}

__global__ __launch_bounds__(256) void scan2_kernel(int* __restrict__ blocksums) {
  __shared__ int sd[256];
  const int t = threadIdx.x;
  int v = (t < kScanBlocks) ? blocksums[t] : 0;
  sd[t] = v;
  __syncthreads();
  for (int off = 1; off < 256; off <<= 1) {
    int x = (t >= off) ? sd[t - off] : 0;
    __syncthreads();
    sd[t] += x;
    __syncthreads();
  }
  if (t < kScanBlocks) blocksums[t] = sd[t] - v;
}

__global__ __launch_bounds__(256) void scan3_kernel(int* __restrict__ row_start,
                                                    const int* __restrict__ blocksums,
                                                    int* __restrict__ cursor) {
  const int i = blockIdx.x * 256 + threadIdx.x;
  if (i < kNodes) {
    int r = row_start[i] + blocksums[blockIdx.x];
    row_start[i] = r;
    cursor[i] = r;
  }
}

__global__ __launch_bounds__(256) void fill_kernel(const int* __restrict__ edges,
                                                   int* __restrict__ cursor,
                                                   unsigned* __restrict__ packed) {
  int e = blockIdx.x * 256 + threadIdx.x;
  if (e < kEdges) {
    const int et  = edges[e * 3 + 0];
    const int src = edges[e * 3 + 1];
    const int tgt = edges[e * 3 + 2];
    const int pos = atomicAdd(&cursor[tgt], 1);
    packed[pos] = (unsigned)(src * 4 + et);  // row index into y[(src,t)][128]
  }
}

// ---------------- transform: y[u][t*128+c] = h[u] @ W_t ----------------
__global__ __launch_bounds__(256) void transform_kernel(
    const float* __restrict__ h,     // [N][128]
    const float* __restrict__ W,     // [4][128][128]
    uint16_t* __restrict__ y16) {    // [N][512] bf16
  __shared__ float Sh[32 * 128];  // 16 KB
  const int tid = threadIdx.x;
  const int t  = blockIdx.x & 3;
  const int node0 = (blockIdx.x >> 2) * 32;
  const int nvalid = min(32, kNodes - node0);

  {
    const float4* hsrc = (const float4*)(h + (size_t)node0 * kHid);
    float4* sdst = (float4*)Sh;
#pragma unroll
    for (int i = 0; i < 4; ++i) {
      const int idx = tid + i * 256;
      const int nl = idx >> 5;
      sdst[idx] = (nl < nvalid) ? hsrc[idx] : make_float4(0.f, 0.f, 0.f, 0.f);
    }
  }
  __syncthreads();

  const int lane = tid & 31;
  const int n0 = (tid >> 5) * 4;
  float acc[4][4] = {};
  const float4* __restrict__ W4 = (const float4*)(W + (size_t)t * 16384);

  for (int k = 0; k < 128; k += 4) {
    const float4 w0 = W4[(k + 0) * 32 + lane];
    const float4 w1 = W4[(k + 1) * 32 + lane];
    const float4 w2 = W4[(k + 2) * 32 + lane];
    const float4 w3 = W4[(k + 3) * 32 + lane];
#pragma unroll
    for (int n = 0; n < 4; ++n) {
      const float4 s = *(const float4*)&Sh[(n0 + n) * kHid + k];
      acc[n][0] += s.x * w0.x + s.y * w1.x + s.z * w2.x + s.w * w3.x;
      acc[n][1] += s.x * w0.y + s.y * w1.y + s.z * w2.y + s.w * w3.y;
      acc[n][2] += s.x * w0.z + s.y * w1.z + s.z * w2.z + s.w * w3.z;
      acc[n][3] += s.x * w0.w + s.y * w1.w + s.z * w2.w + s.w * w3.w;
    }
  }

#pragma unroll
  for (int n = 0; n < 4; ++n) {
    const int node = node0 + n0 + n;
    if (node < kNodes) {
      const uint32_t lo = f2bf(acc[n][0]) | (f2bf(acc[n][1]) << 16);
      const uint32_t hi = f2bf(acc[n][2]) | (f2bf(acc[n][3]) << 16);
      *(uint2*)&y16[(size_t)node * 512 + t * 128 + lane * 4] = make_uint2(lo, hi);
    }
  }
}

// ---------------- gather ----------------
__global__ __launch_bounds__(256) void gather_kernel(
    const uint32_t* __restrict__ y2,
    const uint32_t* __restrict__ packed,
    const int* __restrict__ row_start,
    const int* __restrict__ counts,
    const int* __restrict__ degT,
    const float* __restrict__ TB,
    float* __restrict__ msg) {
  const int tid = threadIdx.x;
  const int lane = tid & 63;
  const int v = blockIdx.x * 4 + (tid >> 6);
  const int s0 = row_start[v];
  const int cnt = counts[v];
  float a0 = 0.f, a1 = 0.f;
  int e = 0;
  for (; e + 4 <= cnt; e += 4) {
    const uint32_t p0 = packed[s0 + e + 0];
    const uint32_t p1 = packed[s0 + e + 1];
    const uint32_t p2 = packed[s0 + e + 2];
    const uint32_t p3 = packed[s0 + e + 3];
    const uint32_t u0 = y2[(size_t)p0 * 64 + lane];
    const uint32_t u1 = y2[(size_t)p1 * 64 + lane];
    const uint32_t u2 = y2[(size_t)p2 * 64 + lane];
    const uint32_t u3 = y2[(size_t)p3 * 64 + lane];
    a0 += __uint_as_float(u0 << 16) + __uint_as_float(u1 << 16) +
          __uint_as_float(u2 << 16) + __uint_as_float(u3 << 16);
    a1 += __uint_as_float(u0 & 0xFFFF0000u) + __uint_as_float(u1 & 0xFFFF0000u) +
          __uint_as_float(u2 & 0xFFFF0000u) + __uint_as_float(u3 & 0xFFFF0000u);
  }
  for (; e < cnt; ++e) {
    const uint32_t p = packed[s0 + e];
    const uint32_t u = y2[(size_t)p * 64 + lane];
    a0 += __uint_as_float(u << 16);
    a1 += __uint_as_float(u & 0xFFFF0000u);
  }
  const int4 dg = *(const int4*)&degT[v * 4];
  const float2 b0 = *(const float2*)&TB[0 * 128 + lane * 2];
  const float2 b1 = *(const float2*)&TB[1 * 128 + lane * 2];
  const float2 b2 = *(const float2*)&TB[2 * 128 + lane * 2];
  const float2 b3 = *(const float2*)&TB[3 * 128 + lane * 2];
  a0 += dg.x * b0.x + dg.y * b1.x + dg.z * b2.x + dg.w * b3.x;
  a1 += dg.x * b0.y + dg.y * b1.y + dg.z * b2.y + dg.w * b3.y;
  *(float2*)&msg[(size_t)v * kHid + lane * 2] = make_float2(a0, a1);
}

// ---------------- fallback message kernel ----------------
__global__ __launch_bounds__(256, 2) void message_fb_kernel(
    const float* __restrict__ hin,
    const unsigned* __restrict__ packed,
    const int* __restrict__ row_start,
    const int* __restrict__ counts,
    const float* __restrict__ W,
    const float* __restrict__ TB,
    const int* __restrict__ degT,
    float* __restrict__ msg) {
  __shared__ float S[32 * 512];
  const int tid = threadIdx.x;
  {
    const int g = tid >> 7;
    const int j = tid & 127;
    for (int i = 0; i < 16; ++i) {
      const int nl = g * 16 + i;
      const int v = blockIdx.x * 32 + nl;
      if (v >= kNodes) break;
      const int s0  = row_start[v];
      const int cnt = counts[v];
      float a0 = 0.f, a1 = 0.f, a2 = 0.f, a3 = 0.f;
      for (int e = 0; e < cnt; ++e) {
        const unsigned p = packed[s0 + e];
        const int src = (int)(p >> 2);
        const int t = (int)(p & 3u);
        const float val = hin[(size_t)src * kHid + j];
        a0 += (t == 0) ? val : 0.f;
        a1 += (t == 1) ? val : 0.f;
        a2 += (t == 2) ? val : 0.f;
        a3 += (t == 3) ? val : 0.f;
      }
      float* Sn = &S[nl * 512];
      Sn[j] = a0; Sn[128 + j] = a1; Sn[256 + j] = a2; Sn[384 + j] = a3;
    }
  }
  __syncthreads();

  const int lane = tid & 31;
  const int jj = lane * 4;
  const int n0 = (tid >> 5) * 4;
  float acc[4][4] = {};
  const float4* __restrict__ W4 = (const float4*)W;
  for (int tk = 0; tk < 512; tk += 4) {
    const float4 w0 = W4[(size_t)(tk + 0) * 32 + lane];
    const float4 w1 = W4[(size_t)(tk + 1) * 32 + lane];
    const float4 w2 = W4[(size_t)(tk + 2) * 32 + lane];
    const float4 w3 = W4[(size_t)(tk + 3) * 32 + lane];
#pragma unroll
    for (int n = 0; n < 4; ++n) {
      const float4 s = *(const float4*)&S[(n0 + n) * 512 + tk];
      acc[n][0] += s.x * w0.x + s.y * w1.x + s.z * w2.x + s.w * w3.x;
      acc[n][1] += s.x * w0.y + s.y * w1.y + s.z * w2.y + s.w * w3.y;
      acc[n][2] += s.x * w0.z + s.y * w1.z + s.z * w2.z + s.w * w3.z;
      acc[n][3] += s.x * w0.w + s.y * w1.w + s.z * w2.w + s.w * w3.w;
    }
  }
  const float4 B0 = *(const float4*)&TB[0 * 128 + jj];
  const float4 B1 = *(const float4*)&TB[1 * 128 + jj];
  const float4 B2 = *(const float4*)&TB[2 * 128 + jj];
  const float4 B3 = *(const float4*)&TB[3 * 128 + jj];
#pragma unroll
  for (int n = 0; n < 4; ++n) {
    const int v = blockIdx.x * 32 + n0 + n;
    if (v < kNodes) {
      const int4 dg = *(const int4*)&degT[(size_t)v * 4];
      float4 o;
      o.x = acc[n][0] + dg.x * B0.x + dg.y * B1.x + dg.z * B2.x + dg.w * B3.x;
      o.y = acc[n][1] + dg.x * B0.y + dg.y * B1.y + dg.z * B2.y + dg.w * B3.y;
      o.z = acc[n][2] + dg.x * B0.z + dg.y * B1.z + dg.z * B2.z + dg.w * B3.z;
      o.w = acc[n][3] + dg.x * B0.w + dg.y * B1.w + dg.z * B2.w + dg.w * B3.w;
      *(float4*)&msg[(size_t)v * kHid + jj] = o;
    }
  }
}

// ---------------- GRU: LDS-tiled GEMM, 64 nodes x 384 cols per block ----------------

__device__ __forceinline__ float sigf(float x) {
  return 1.f / (1.f + __expf(-x));
}
__device__ __forceinline__ float tanh_fast(float x) {
  x = fminf(fmaxf(x, -15.f), 15.f);
  const float e2 = __expf(2.f * x);
  return (e2 - 1.f) / (e2 + 1.f);
}

// In-place safe (hin == hout): block owns 64 full rows; all global reads of
// those rows (A staging + epilogue hp) precede the epilogue writes in block
// program order, and no other block touches them.
__global__ __launch_bounds__(256, 2) void gru_kernel(
    const float* __restrict__ msg,
    const float* __restrict__ hin,
    const float* __restrict__ K,    // [128][384]  cols: z | r | h
    const float* __restrict__ R,    // [128][384]
    const float* __restrict__ gb,   // [2][384]
    float* __restrict__ hout) {
  __shared__ float At[2][16][68];   // [m][kk][node], pad 68 -> 2-way banks
  __shared__ float Bt[2][16][384];  // [m][kk][col]
  const int tid = threadIdx.x;
  const int node0 = blockIdx.x * 64;
  const int cg = tid >> 4;   // 16 col groups: cols cg*8..cg*8+7 within each gate
  const int ng = tid & 15;   // node group: local nodes ng*4..ng*4+3

  float accZ[4][8] = {}, accR[4][8] = {}, accXH[4][8] = {}, accRH[4][8] = {};

  const float4* __restrict__ K4 = (const float4*)K;
  const float4* __restrict__ R4 = (const float4*)R;

  // staging indices (constant across k0)
  const int sn = tid >> 2;   // 0..63 node for A staging
  const int sj = tid & 3;    // k-subquad

  for (int k0 = 0; k0 < 128; k0 += 16) {
    __syncthreads();
    // ---- stage A (msg, h) k-major with transpose
    {
      float4 vm = make_float4(0.f, 0.f, 0.f, 0.f);
      float4 vh = vm;
      const int node = node0 + sn;
      if (node < kNodes) {
        vm = *(const float4*)&msg[(size_t)node * kHid + k0 + sj * 4];
        vh = *(const float4*)&hin[(size_t)node * kHid + k0 + sj * 4];
      }
      At[0][sj * 4 + 0][sn] = vm.x;
      At[0][sj * 4 + 1][sn] = vm.y;
      At[0][sj * 4 + 2][sn] = vm.z;
      At[0][sj * 4 + 3][sn] = vm.w;
      At[1][sj * 4 + 0][sn] = vh.x;
      At[1][sj * 4 + 1][sn] = vh.y;
      At[1][sj * 4 + 2][sn] = vh.z;
      At[1][sj * 4 + 3][sn] = vh.w;
    }
    // ---- stage B (K, R): 16 rows x 96 float4 each
#pragma unroll
    for (int i = 0; i < 6; ++i) {
      const int idx = tid + i * 256;       // 0..1535
      const int row = idx / 96;
      const int c4 = idx - row * 96;
      *(float4*)&Bt[0][row][c4 * 4] = K4[(size_t)(k0 + row) * 96 + c4];
      *(float4*)&Bt[1][row][c4 * 4] = R4[(size_t)(k0 + row) * 96 + c4];
    }
    __syncthreads();

    for (int kk = 0; kk < 16; ++kk) {
      const float4 am4 = *(const float4*)&At[0][kk][ng * 4];
      const float4 ah4 = *(const float4*)&At[1][kk][ng * 4];
      const float am[4] = {am4.x, am4.y, am4.z, am4.w};
      const float ah[4] = {ah4.x, ah4.y, ah4.z, ah4.w};
      const int cb = cg * 8;
      // gate z (fused msg*K + h*R)
      {
        const float4 k0v = *(const float4*)&Bt[0][kk][cb];
        const float4 k1v = *(const float4*)&Bt[0][kk][cb + 4];
        const float4 r0v = *(const float4*)&Bt[1][kk][cb];
        const float4 r1v = *(const float4*)&Bt[1][kk][cb + 4];
        const float bk[8] = {k0v.x, k0v.y, k0v.z, k0v.w, k1v.x, k1v.y, k1v.z, k1v.w};
        const float br[8] = {r0v.x, r0v.y, r0v.z, r0v.w, r1v.x, r1v.y, r1v.z, r1v.w};
#pragma unroll
        for (int n = 0; n < 4; ++n)
#pragma unroll
          for (int c = 0; c < 8; ++c)
            accZ[n][c] += am[n] * bk[c] + ah[n] * br[c];
      }
      // gate r (fused)
      {
        const float4 k0v = *(const float4*)&Bt[0][kk][128 + cb];
        const float4 k1v = *(const float4*)&Bt[0][kk][128 + cb + 4];
        const float4 r0v = *(const float4*)&Bt[1][kk][128 + cb];
        const float4 r1v = *(const float4*)&Bt[1][kk][128 + cb + 4];
        const float bk[8] = {k0v.x, k0v.y, k0v.z, k0v.w, k1v.x, k1v.y, k1v.z, k1v.w};
        const float br[8] = {r0v.x, r0v.y, r0v.z, r0v.w, r1v.x, r1v.y, r1v.z, r1v.w};
#pragma unroll
        for (int n = 0; n < 4; ++n)
#pragma unroll
          for (int c = 0; c < 8; ++c)
            accR[n][c] += am[n] * bk[c] + ah[n] * br[c];
      }
      // gate h (xh and rh kept separate: hh = tanh(xh + r*rh))
      {
        const float4 k0v = *(const float4*)&Bt[0][kk][256 + cb];
        const float4 k1v = *(const float4*)&Bt[0][kk][256 + cb + 4];
        const float4 r0v = *(const float4*)&Bt[1][kk][256 + cb];
        const float4 r1v = *(const float4*)&Bt[1][kk][256 + cb + 4];
        const float bk[8] = {k0v.x, k0v.y, k0v.z, k0v.w, k1v.x, k1v.y, k1v.z, k1v.w};
        const float br[8] = {r0v.x, r0v.y, r0v.z, r0v.w, r1v.x, r1v.y, r1v.z, r1v.w};
#pragma unroll
        for (int n = 0; n < 4; ++n)
#pragma unroll
          for (int c = 0; c < 8; ++c) {
            accXH[n][c] += am[n] * bk[c];
            accRH[n][c] += ah[n] * br[c];
          }
      }
    }
  }

  // ---- epilogue (per-thread local; combined biases)
  const int cb = cg * 8;
  float bz[8], brr[8], bxh[8], brh[8];
  {
    const float4 a0 = *(const float4*)&gb[cb];
    const float4 a1 = *(const float4*)&gb[cb + 4];
    const float4 b0 = *(const float4*)&gb[384 + cb];
    const float4 b1 = *(const float4*)&gb[384 + cb + 4];
    bz[0] = a0.x + b0.x; bz[1] = a0.y + b0.y; bz[2] = a0.z + b0.z; bz[3] = a0.w + b0.w;
    bz[4] = a1.x + b1.x; bz[5] = a1.y + b1.y; bz[6] = a1.z + b1.z; bz[7] = a1.w + b1.w;
    const float4 c0 = *(const float4*)&gb[128 + cb];
    const float4 c1 = *(const float4*)&gb[128 + cb + 4];
    const float4 d0 = *(const float4*)&gb[384 + 128 + cb];
    const float4 d1 = *(const float4*)&gb[384 + 128 + cb + 4];
    brr[0] = c0.x + d0.x; brr[1] = c0.y + d0.y; brr[2] = c0.z + d0.z; brr[3] = c0.w + d0.w;
    brr[4] = c1.x + d1.x; brr[5] = c1.y + d1.y; brr[6] = c1.z + d1.z; brr[7] = c1.w + d1.w;
    const float4 e0 = *(const float4*)&gb[256 + cb];
    const float4 e1 = *(const float4*)&gb[256 + cb + 4];
    bxh[0] = e0.x; bxh[1] = e0.y; bxh[2] = e0.z; bxh[3] = e0.w;
    bxh[4] = e1.x; bxh[5] = e1.y; bxh[6] = e1.z; bxh[7] = e1.w;
    const float4 f0 = *(const float4*)&gb[384 + 256 + cb];
    const float4 f1 = *(const float4*)&gb[384 + 256 + cb + 4];
    brh[0] = f0.x; brh[1] = f0.y; brh[2] = f0.z; brh[3] = f0.w;
    brh[4] = f1.x; brh[5] = f1.y; brh[6] = f1.z; brh[7] = f1.w;
  }

#pragma unroll
  for (int n = 0; n < 4; ++n) {
    const int node = node0 + ng * 4 + n;
    if (node >= kNodes) continue;
    const float4 hp0 = *(const float4*)&hin[(size_t)node * kHid + cb];
    const float4 hp1 = *(const float4*)&hin[(size_t)node * kHid + cb + 4];
    const float hp[8] = {hp0.x, hp0.y, hp0.z, hp0.w, hp1.x, hp1.y, hp1.z, hp1.w};
    float o[8];
#pragma unroll
    for (int c = 0; c < 8; ++c) {
      const float z = sigf(accZ[n][c] + bz[c]);
      const float r = sigf(accR[n][c] + brr[c]);
      const float hh = tanh_fast(accXH[n][c] + bxh[c] + r * (accRH[n][c] + brh[c]));
      o[c] = z * hp[c] + (1.f - z) * hh;
    }
    *(float4*)&hout[(size_t)node * kHid + cb]     = make_float4(o[0], o[1], o[2], o[3]);
    *(float4*)&hout[(size_t)node * kHid + cb + 4] = make_float4(o[4], o[5], o[6], o[7]);
  }
}

extern "C" void kernel_launch(void* const* d_in, const int* in_sizes, int n_in,
                              void* d_out, int out_size, void* d_ws, size_t ws_size,
                              hipStream_t stream) {
  const float* states = (const float*)d_in[0];
  const int*   edges  = (const int*)d_in[1];
  const float* W      = (const float*)d_in[2];
  const float* TB     = (const float*)d_in[3];
  const float* K      = (const float*)d_in[4];
  const float* R      = (const float*)d_in[5];
  const float* gb     = (const float*)d_in[6];
  float* out = (float*)d_out;

  if (ws_size < kWsFallback) return;

  char* ws = (char*)d_ws;
  int*      counts    = (int*)(ws + oCounts);
  int*      degT      = (int*)(ws + oDegT);
  int*      row_start = (int*)(ws + oRowStart);
  int*      cursor    = (int*)(ws + oCursor);
  int*      blocksums = (int*)(ws + oBlockSums);
  unsigned* packed    = (unsigned*)(ws + oPacked);
  float*    msg       = (float*)(ws + oMsg);
  uint16_t* y16       = (uint16_t*)(ws + oY);
  uint32_t* y2        = (uint32_t*)(ws + oY);

  hipMemsetAsync(counts, 0, oRowStart - oCounts, stream);
  count_kernel<<<kEdges / 256, 256, 0, stream>>>(edges, counts, degT);
  scan1_kernel<<<kScanBlocks, 256, 0, stream>>>(counts, row_start, blocksums);
  scan2_kernel<<<1, 256, 0, stream>>>(blocksums);
  scan3_kernel<<<kScanBlocks, 256, 0, stream>>>(row_start, blocksums, cursor);
  fill_kernel<<<kEdges / 256, 256, 0, stream>>>(edges, cursor, packed);

  const int gru_blocks = (kNodes + 63) / 64;  // 782

  if (ws_size >= kWsNeeded) {
    const int tf_blocks = ((kNodes + 31) / 32) * 4;  // 6252
    const int ga_blocks = kNodes / 4;                // 12500
    transform_kernel<<<tf_blocks, 256, 0, stream>>>(states, W, y16);
    gather_kernel<<<ga_blocks, 256, 0, stream>>>(y2, packed, row_start, counts,
                                                 degT, TB, msg);
    gru_kernel<<<gru_blocks, 256, 0, stream>>>(msg, states, K, R, gb, out);
    transform_kernel<<<tf_blocks, 256, 0, stream>>>(out, W, y16);
    gather_kernel<<<ga_blocks, 256, 0, stream>>>(y2, packed, row_start, counts,
                                                 degT, TB, msg);
    gru_kernel<<<gru_blocks, 256, 0, stream>>>(msg, out, K, R, gb, out);
  } else {
    const int msg_blocks = (kNodes + 31) / 32;  // 1563
    message_fb_kernel<<<msg_blocks, 256, 0, stream>>>(states, packed, row_start,
                                                      counts, W, TB, degT, msg);
    gru_kernel<<<gru_blocks, 256, 0, stream>>>(msg, states, K, R, gb, out);
    message_fb_kernel<<<msg_blocks, 256, 0, stream>>>(out, packed, row_start,
                                                      counts, W, TB, degT, msg);
    gru_kernel<<<gru_blocks, 256, 0, stream>>>(msg, out, K, R, gb, out);
  }
}

// Round 4
// 593.878 us; speedup vs baseline: 3.4960x; 1.5582x over previous
//
#include <hip/hip_runtime.h>
#include <stdint.h>

namespace {
constexpr int kNodes = 50000;
constexpr int kEdges = 800000;
constexpr int kHid   = 128;
constexpr int kMT    = kNodes / 16;   // 3125 M-tiles (exact)
constexpr int kScanBlocks = (kNodes + 255) / 256;  // 196

// workspace layout (bytes)
constexpr size_t oCounts    = 0;         // 200000 (in-degree per node)
constexpr size_t oCursor    = 200704;    // 200000 (scan -> row_start -> row_end)
constexpr size_t oBlockSums = 401408;    // 784
constexpr size_t oBpack     = 402432;    // 655360 (packed MFMA B-frags)
constexpr size_t oPacked    = 1057792;   // 800000*4 = 3200000 (CSR edge list)
constexpr size_t oMsg       = 4257792;   // 50000*128*4 = 25600000 (fp32 msg)
constexpr size_t oY         = 29857792;  // 50000*512*2 = 51200000 (bf16 y)
constexpr size_t kWsNeeded   = oY + 51200000;  // 81,057,792
constexpr size_t kWsFallback = oY;             // fallback path doesn't use oY

// Bpack sub-offsets (bytes relative to oBpack)
constexpr size_t bKhi = 0,      bKlo = 98304,  bRhi = 196608,
                 bRlo = 294912, bWhi = 393216, bWlo = 524288;
}

typedef __attribute__((ext_vector_type(8))) short short8;
typedef __attribute__((ext_vector_type(4))) float f32x4;

union ABFrag { short8 v; uint16_t u[8]; uint4 q; };

__device__ __forceinline__ uint16_t f2bf(float x) {
  uint32_t u = __float_as_uint(x);
  return (uint16_t)((u + 0x7FFFu + ((u >> 16) & 1u)) >> 16);
}
__device__ __forceinline__ float bf2f(uint16_t h) {
  return __uint_as_float(((uint32_t)h) << 16);
}

// ---------------- CSR build ----------------

__global__ __launch_bounds__(256) void count_kernel(const int* __restrict__ edges,
                                                    int* __restrict__ counts) {
  int e = blockIdx.x * 256 + threadIdx.x;
  if (e < kEdges) atomicAdd(&counts[edges[e * 3 + 2]], 1);
}

__global__ __launch_bounds__(256) void scan1_kernel(const int* __restrict__ counts,
                                                    int* __restrict__ cursor,
                                                    int* __restrict__ blocksums) {
  __shared__ int sd[256];
  const int t = threadIdx.x;
  const int i = blockIdx.x * 256 + t;
  int v = (i < kNodes) ? counts[i] : 0;
  sd[t] = v;
  __syncthreads();
  for (int off = 1; off < 256; off <<= 1) {
    int x = (t >= off) ? sd[t - off] : 0;
    __syncthreads();
    sd[t] += x;
    __syncthreads();
  }
  if (i < kNodes) cursor[i] = sd[t] - v;  // exclusive within block
  if (t == 255) blocksums[blockIdx.x] = sd[255];
}

__global__ __launch_bounds__(256) void scan2_kernel(int* __restrict__ blocksums) {
  __shared__ int sd[256];
  const int t = threadIdx.x;
  int v = (t < kScanBlocks) ? blocksums[t] : 0;
  sd[t] = v;
  __syncthreads();
  for (int off = 1; off < 256; off <<= 1) {
    int x = (t >= off) ? sd[t - off] : 0;
    __syncthreads();
    sd[t] += x;
    __syncthreads();
  }
  if (t < kScanBlocks) blocksums[t] = sd[t] - v;
}

__global__ __launch_bounds__(256) void scan3_kernel(int* __restrict__ cursor,
                                                    const int* __restrict__ blocksums) {
  const int i = blockIdx.x * 256 + threadIdx.x;
  if (i < kNodes) cursor[i] += blocksums[blockIdx.x];
}

__global__ __launch_bounds__(256) void fill_kernel(const int* __restrict__ edges,
                                                   int* __restrict__ cursor,
                                                   unsigned* __restrict__ packed) {
  int e = blockIdx.x * 256 + threadIdx.x;
  if (e < kEdges) {
    const int et  = edges[e * 3 + 0];
    const int src = edges[e * 3 + 1];
    const int tgt = edges[e * 3 + 2];
    const int pos = atomicAdd(&cursor[tgt], 1);
    packed[pos] = (unsigned)(src * 4 + et);  // row index into y[(src,t)][128]
  }
  // after this kernel cursor[v] = row_end(v); row_start = row_end - counts
}

// ---------------- pack B operands into MFMA-frag order ----------------
// frag layout (16x16x32): lane holds B[k=quad*8+j][n=lane&15], j=0..7.
// K/R packed as [kt][nt(24)][lane(64)][8]; W packed as [kt][nt(32)][lane(64)][8].
__global__ __launch_bounds__(256) void pack_b_kernel(
    const float* __restrict__ K,   // [128][384]
    const float* __restrict__ R,   // [128][384]
    const float* __restrict__ W,   // [4][128][128]
    uint16_t* __restrict__ bp) {   // base of Bpack region
  const int idx = blockIdx.x * 256 + threadIdx.x;
  uint16_t* khi = bp + bKhi / 2;
  uint16_t* klo = bp + bKlo / 2;
  uint16_t* rhi = bp + bRhi / 2;
  uint16_t* rlo = bp + bRlo / 2;
  uint16_t* whi = bp + bWhi / 2;
  uint16_t* wlo = bp + bWlo / 2;
  if (idx < 128 * 384) {
    const int k = idx / 384, c = idx % 384;
    const int kt = k >> 5, quad = (k >> 3) & 3, j = k & 7;
    const int nt = c >> 4, ln = (c & 15) | (quad << 4);
    const size_t o = ((size_t)(kt * 24 + nt) * 64 + ln) * 8 + j;
    const float kv = K[k * 384 + c];
    const float rv = R[k * 384 + c];
    const uint16_t kh = f2bf(kv), rh = f2bf(rv);
    khi[o] = kh; klo[o] = f2bf(kv - bf2f(kh));
    rhi[o] = rh; rlo[o] = f2bf(rv - bf2f(rh));
  } else if (idx < 128 * 384 + 128 * 512) {
    const int i2 = idx - 128 * 384;
    const int k = i2 / 512, c = i2 % 512;       // c' = t*128 + cc
    const int t = c >> 7, cc = c & 127;
    const float wv = W[((size_t)t * 128 + k) * 128 + cc];
    const int kt = k >> 5, quad = (k >> 3) & 3, j = k & 7;
    const int nt = c >> 4, ln = (c & 15) | (quad << 4);
    const size_t o = ((size_t)(kt * 32 + nt) * 64 + ln) * 8 + j;
    const uint16_t wh = f2bf(wv);
    whi[o] = wh; wlo[o] = f2bf(wv - bf2f(wh));
  }
}

// ---------------- transform (MFMA): y[u][c'] = (h[u] @ W_{c'>>7})_{c'&127} + TB[c'] ----------------
// grid: 782 blocks x 4 waves; wave = one 16-node M-tile x 512 cols. No LDS.
__global__ __launch_bounds__(256, 2) void transform_mfma(
    const float* __restrict__ h,       // [N][128]
    const uint16_t* __restrict__ bp,   // Bpack region
    const float* __restrict__ TB,      // [4][128] flat = [512]
    uint16_t* __restrict__ y16) {      // [N][512] bf16 (bias included)
  const int tid = threadIdx.x;
  const int mt = blockIdx.x * 4 + (tid >> 6);
  if (mt >= kMT) return;
  const int lane = tid & 63;
  const int col = lane & 15, quad = lane >> 4;

  const uint4* __restrict__ Whi = (const uint4*)(bp + bWhi / 2);
  const uint4* __restrict__ Wlo = (const uint4*)(bp + bWlo / 2);

  f32x4 acc[32];
#pragma unroll
  for (int nt = 0; nt < 32; ++nt) acc[nt] = (f32x4){0.f, 0.f, 0.f, 0.f};

  const float* hrow = h + (size_t)(mt * 16 + col) * kHid + quad * 8;

#pragma unroll
  for (int kt = 0; kt < 4; ++kt) {
    const float4 a0 = *(const float4*)(hrow + kt * 32);
    const float4 a1 = *(const float4*)(hrow + kt * 32 + 4);
    const float av[8] = {a0.x, a0.y, a0.z, a0.w, a1.x, a1.y, a1.z, a1.w};
    ABFrag ahi, alo;
#pragma unroll
    for (int j = 0; j < 8; ++j) {
      const uint16_t hb = f2bf(av[j]);
      ahi.u[j] = hb;
      alo.u[j] = f2bf(av[j] - bf2f(hb));
    }
#pragma unroll
    for (int nt = 0; nt < 32; ++nt) {
      ABFrag bh, bl;
      bh.q = Whi[(size_t)(kt * 32 + nt) * 64 + lane];
      bl.q = Wlo[(size_t)(kt * 32 + nt) * 64 + lane];
      acc[nt] = __builtin_amdgcn_mfma_f32_16x16x32_bf16(ahi.v, bh.v, acc[nt], 0, 0, 0);
      acc[nt] = __builtin_amdgcn_mfma_f32_16x16x32_bf16(ahi.v, bl.v, acc[nt], 0, 0, 0);
      acc[nt] = __builtin_amdgcn_mfma_f32_16x16x32_bf16(alo.v, bh.v, acc[nt], 0, 0, 0);
    }
  }

  // epilogue: C/D layout col = lane&15, row = quad*4 + reg
#pragma unroll
  for (int nt = 0; nt < 32; ++nt) {
    const int c = nt * 16 + col;
    const float bias = TB[c];
#pragma unroll
    for (int r = 0; r < 4; ++r) {
      const int node = mt * 16 + quad * 4 + r;
      y16[(size_t)node * 512 + c] = f2bf(acc[nt][r] + bias);
    }
  }
}

// ---------------- gather: msg[v] = sum_e y[src_e*4+t_e]  (bias already in y) ----------------
__global__ __launch_bounds__(256) void gather_kernel(
    const uint32_t* __restrict__ y2,      // y as uint32 pairs: [row][64]
    const uint32_t* __restrict__ packed,
    const int* __restrict__ rowend,
    const int* __restrict__ counts,
    float* __restrict__ msg) {
  const int tid = threadIdx.x;
  const int lane = tid & 63;
  const int v = blockIdx.x * 4 + (tid >> 6);
  const int cnt = counts[v];
  const int s0 = rowend[v] - cnt;
  float a0 = 0.f, a1 = 0.f;
  int e = 0;
  for (; e + 4 <= cnt; e += 4) {
    const uint32_t p0 = packed[s0 + e + 0];
    const uint32_t p1 = packed[s0 + e + 1];
    const uint32_t p2 = packed[s0 + e + 2];
    const uint32_t p3 = packed[s0 + e + 3];
    const uint32_t u0 = y2[(size_t)p0 * 64 + lane];
    const uint32_t u1 = y2[(size_t)p1 * 64 + lane];
    const uint32_t u2 = y2[(size_t)p2 * 64 + lane];
    const uint32_t u3 = y2[(size_t)p3 * 64 + lane];
    a0 += __uint_as_float(u0 << 16) + __uint_as_float(u1 << 16) +
          __uint_as_float(u2 << 16) + __uint_as_float(u3 << 16);
    a1 += __uint_as_float(u0 & 0xFFFF0000u) + __uint_as_float(u1 & 0xFFFF0000u) +
          __uint_as_float(u2 & 0xFFFF0000u) + __uint_as_float(u3 & 0xFFFF0000u);
  }
  for (; e < cnt; ++e) {
    const uint32_t p = packed[s0 + e];
    const uint32_t u = y2[(size_t)p * 64 + lane];
    a0 += __uint_as_float(u << 16);
    a1 += __uint_as_float(u & 0xFFFF0000u);
  }
  *(float2*)&msg[(size_t)v * kHid + lane * 2] = make_float2(a0, a1);
}

// ---------------- GRU (MFMA): gates = msg@K + h@R, fused epilogue ----------------
// grid: 782 blocks x 4 waves; wave = one 16-node M-tile x 384 cols. No LDS.
// In-place safe (hin == hout): each wave only reads/writes its own 16 rows,
// all reads precede the epilogue stores in wave program order.
__device__ __forceinline__ float sigf(float x) { return 1.f / (1.f + __expf(-x)); }
__device__ __forceinline__ float tanh_fast(float x) {
  x = fminf(fmaxf(x, -15.f), 15.f);
  const float e2 = __expf(2.f * x);
  return (e2 - 1.f) / (e2 + 1.f);
}

__global__ __launch_bounds__(256, 2) void gru_mfma(
    const float* __restrict__ msg,     // [N][128]
    const float* __restrict__ hin,     // [N][128]
    const uint16_t* __restrict__ bp,   // Bpack region
    const float* __restrict__ gb,      // [2][384]
    float* __restrict__ hout) {
  const int tid = threadIdx.x;
  const int mt = blockIdx.x * 4 + (tid >> 6);
  if (mt >= kMT) return;
  const int lane = tid & 63;
  const int col = lane & 15, quad = lane >> 4;

  const uint4* __restrict__ Khi = (const uint4*)(bp + bKhi / 2);
  const uint4* __restrict__ Klo = (const uint4*)(bp + bKlo / 2);
  const uint4* __restrict__ Rhi = (const uint4*)(bp + bRhi / 2);
  const uint4* __restrict__ Rlo = (const uint4*)(bp + bRlo / 2);

  f32x4 accZR[16], accXH[8], accRH[8];
#pragma unroll
  for (int i = 0; i < 16; ++i) accZR[i] = (f32x4){0.f, 0.f, 0.f, 0.f};
#pragma unroll
  for (int i = 0; i < 8; ++i) { accXH[i] = (f32x4){0.f, 0.f, 0.f, 0.f};
                                accRH[i] = (f32x4){0.f, 0.f, 0.f, 0.f}; }

  const float* mrow = msg + (size_t)(mt * 16 + col) * kHid + quad * 8;
  const float* hrow = hin + (size_t)(mt * 16 + col) * kHid + quad * 8;

#pragma unroll
  for (int kt = 0; kt < 4; ++kt) {
    ABFrag mhi, mlo, hhi, hlo;
    {
      const float4 a0 = *(const float4*)(mrow + kt * 32);
      const float4 a1 = *(const float4*)(mrow + kt * 32 + 4);
      const float4 b0 = *(const float4*)(hrow + kt * 32);
      const float4 b1 = *(const float4*)(hrow + kt * 32 + 4);
      const float mv[8] = {a0.x, a0.y, a0.z, a0.w, a1.x, a1.y, a1.z, a1.w};
      const float hv[8] = {b0.x, b0.y, b0.z, b0.w, b1.x, b1.y, b1.z, b1.w};
#pragma unroll
      for (int j = 0; j < 8; ++j) {
        uint16_t t = f2bf(mv[j]);
        mhi.u[j] = t; mlo.u[j] = f2bf(mv[j] - bf2f(t));
        t = f2bf(hv[j]);
        hhi.u[j] = t; hlo.u[j] = f2bf(hv[j] - bf2f(t));
      }
    }
    // z,r gates: cols 0..255, accumulate msg@K + h@R together
#pragma unroll
    for (int nt = 0; nt < 16; ++nt) {
      ABFrag kh, kl, rh, rl;
      kh.q = Khi[(size_t)(kt * 24 + nt) * 64 + lane];
      kl.q = Klo[(size_t)(kt * 24 + nt) * 64 + lane];
      rh.q = Rhi[(size_t)(kt * 24 + nt) * 64 + lane];
      rl.q = Rlo[(size_t)(kt * 24 + nt) * 64 + lane];
      f32x4 a = accZR[nt];
      a = __builtin_amdgcn_mfma_f32_16x16x32_bf16(mhi.v, kh.v, a, 0, 0, 0);
      a = __builtin_amdgcn_mfma_f32_16x16x32_bf16(mhi.v, kl.v, a, 0, 0, 0);
      a = __builtin_amdgcn_mfma_f32_16x16x32_bf16(mlo.v, kh.v, a, 0, 0, 0);
      a = __builtin_amdgcn_mfma_f32_16x16x32_bf16(hhi.v, rh.v, a, 0, 0, 0);
      a = __builtin_amdgcn_mfma_f32_16x16x32_bf16(hhi.v, rl.v, a, 0, 0, 0);
      a = __builtin_amdgcn_mfma_f32_16x16x32_bf16(hlo.v, rh.v, a, 0, 0, 0);
      accZR[nt] = a;
    }
    // h gate: cols 256..383, xh and rh kept separate
#pragma unroll
    for (int nt = 0; nt < 8; ++nt) {
      ABFrag kh, kl, rh, rl;
      kh.q = Khi[(size_t)(kt * 24 + 16 + nt) * 64 + lane];
      kl.q = Klo[(size_t)(kt * 24 + 16 + nt) * 64 + lane];
      rh.q = Rhi[(size_t)(kt * 24 + 16 + nt) * 64 + lane];
      rl.q = Rlo[(size_t)(kt * 24 + 16 + nt) * 64 + lane];
      f32x4 x = accXH[nt];
      x = __builtin_amdgcn_mfma_f32_16x16x32_bf16(mhi.v, kh.v, x, 0, 0, 0);
      x = __builtin_amdgcn_mfma_f32_16x16x32_bf16(mhi.v, kl.v, x, 0, 0, 0);
      x = __builtin_amdgcn_mfma_f32_16x16x32_bf16(mlo.v, kh.v, x, 0, 0, 0);
      accXH[nt] = x;
      f32x4 y = accRH[nt];
      y = __builtin_amdgcn_mfma_f32_16x16x32_bf16(hhi.v, rh.v, y, 0, 0, 0);
      y = __builtin_amdgcn_mfma_f32_16x16x32_bf16(hhi.v, rl.v, y, 0, 0, 0);
      y = __builtin_amdgcn_mfma_f32_16x16x32_bf16(hlo.v, rh.v, y, 0, 0, 0);
      accRH[nt] = y;
    }
  }

  // ---- epilogue: per-lane cols c = j*16 + col, rows quad*4 + r
#pragma unroll
  for (int j = 0; j < 8; ++j) {
    const int c = j * 16 + col;
    const float bz = gb[c] + gb[384 + c];
    const float br = gb[128 + c] + gb[512 + c];
    const float bx = gb[256 + c];
    const float bh = gb[640 + c];
#pragma unroll
    for (int r = 0; r < 4; ++r) {
      const int node = mt * 16 + quad * 4 + r;
      const float hp = hin[(size_t)node * kHid + c];
      const float z = sigf(accZR[j][r] + bz);
      const float rr = sigf(accZR[8 + j][r] + br);
      const float hh = tanh_fast(accXH[j][r] + bx + rr * (accRH[j][r] + bh));
      hout[(size_t)node * kHid + c] = z * hp + (1.f - z) * hh;
    }
  }
}

// ---------------- fallback path (only if ws too small; proven unused here) ----------------

__global__ __launch_bounds__(256, 2) void message_fb_kernel(
    const float* __restrict__ hin,
    const unsigned* __restrict__ packed,
    const int* __restrict__ rowend,
    const int* __restrict__ counts,
    const float* __restrict__ W,
    const float* __restrict__ TB,
    float* __restrict__ msg) {
  __shared__ float S[32 * 512];
  __shared__ int D[32][4];
  const int tid = threadIdx.x;
  {
    const int g = tid >> 7;
    const int j = tid & 127;
    for (int i = 0; i < 16; ++i) {
      const int nl = g * 16 + i;
      const int v = blockIdx.x * 32 + nl;
      if (v >= kNodes) break;
      const int cnt = counts[v];
      const int s0 = rowend[v] - cnt;
      float a0 = 0.f, a1 = 0.f, a2 = 0.f, a3 = 0.f;
      int d0 = 0, d1 = 0, d2 = 0, d3 = 0;
      for (int e = 0; e < cnt; ++e) {
        const unsigned p = packed[s0 + e];
        const int src = (int)(p >> 2);
        const int t = (int)(p & 3u);
        const float val = hin[(size_t)src * kHid + j];
        a0 += (t == 0) ? val : 0.f;
        a1 += (t == 1) ? val : 0.f;
        a2 += (t == 2) ? val : 0.f;
        a3 += (t == 3) ? val : 0.f;
        d0 += (t == 0); d1 += (t == 1); d2 += (t == 2); d3 += (t == 3);
      }
      float* Sn = &S[nl * 512];
      Sn[j] = a0; Sn[128 + j] = a1; Sn[256 + j] = a2; Sn[384 + j] = a3;
      if (j == 0) { D[nl][0] = d0; D[nl][1] = d1; D[nl][2] = d2; D[nl][3] = d3; }
    }
  }
  __syncthreads();

  const int lane = tid & 31;
  const int jj = lane * 4;
  const int n0 = (tid >> 5) * 4;
  float acc[4][4] = {};
  const float4* __restrict__ W4 = (const float4*)W;
  for (int tk = 0; tk < 512; tk += 4) {
    const float4 w0 = W4[(size_t)(tk + 0) * 32 + lane];
    const float4 w1 = W4[(size_t)(tk + 1) * 32 + lane];
    const float4 w2 = W4[(size_t)(tk + 2) * 32 + lane];
    const float4 w3 = W4[(size_t)(tk + 3) * 32 + lane];
#pragma unroll
    for (int n = 0; n < 4; ++n) {
      const float4 s = *(const float4*)&S[(n0 + n) * 512 + tk];
      acc[n][0] += s.x * w0.x + s.y * w1.x + s.z * w2.x + s.w * w3.x;
      acc[n][1] += s.x * w0.y + s.y * w1.y + s.z * w2.y + s.w * w3.y;
      acc[n][2] += s.x * w0.z + s.y * w1.z + s.z * w2.z + s.w * w3.z;
      acc[n][3] += s.x * w0.w + s.y * w1.w + s.z * w2.w + s.w * w3.w;
    }
  }
  const float4 B0 = *(const float4*)&TB[0 * 128 + jj];
  const float4 B1 = *(const float4*)&TB[1 * 128 + jj];
  const float4 B2 = *(const float4*)&TB[2 * 128 + jj];
  const float4 B3 = *(const float4*)&TB[3 * 128 + jj];
#pragma unroll
  for (int n = 0; n < 4; ++n) {
    const int v = blockIdx.x * 32 + n0 + n;
    if (v < kNodes) {
      float4 o;
      const float d0 = (float)D[n0 + n][0], d1 = (float)D[n0 + n][1];
      const float d2 = (float)D[n0 + n][2], d3 = (float)D[n0 + n][3];
      o.x = acc[n][0] + d0 * B0.x + d1 * B1.x + d2 * B2.x + d3 * B3.x;
      o.y = acc[n][1] + d0 * B0.y + d1 * B1.y + d2 * B2.y + d3 * B3.y;
      o.z = acc[n][2] + d0 * B0.z + d1 * B1.z + d2 * B2.z + d3 * B3.z;
      o.w = acc[n][3] + d0 * B0.w + d1 * B1.w + d2 * B2.w + d3 * B3.w;
      *(float4*)&msg[(size_t)v * kHid + jj] = o;
    }
  }
}

__global__ __launch_bounds__(256, 2) void gru_fb_kernel(
    const float* __restrict__ msg,
    const float* __restrict__ hin,
    const float* __restrict__ K,
    const float* __restrict__ R,
    const float* __restrict__ gb,
    float* __restrict__ hout) {
  __shared__ float At[2][16][68];
  __shared__ float Bt[2][16][384];
  const int tid = threadIdx.x;
  const int node0 = blockIdx.x * 64;
  const int cg = tid >> 4;
  const int ng = tid & 15;

  float accZ[4][8] = {}, accR[4][8] = {}, accXH[4][8] = {}, accRH[4][8] = {};
  const float4* __restrict__ K4 = (const float4*)K;
  const float4* __restrict__ R4 = (const float4*)R;
  const int sn = tid >> 2;
  const int sj = tid & 3;

  for (int k0 = 0; k0 < 128; k0 += 16) {
    __syncthreads();
    {
      float4 vm = make_float4(0.f, 0.f, 0.f, 0.f);
      float4 vh = vm;
      const int node = node0 + sn;
      if (node < kNodes) {
        vm = *(const float4*)&msg[(size_t)node * kHid + k0 + sj * 4];
        vh = *(const float4*)&hin[(size_t)node * kHid + k0 + sj * 4];
      }
      At[0][sj * 4 + 0][sn] = vm.x; At[0][sj * 4 + 1][sn] = vm.y;
      At[0][sj * 4 + 2][sn] = vm.z; At[0][sj * 4 + 3][sn] = vm.w;
      At[1][sj * 4 + 0][sn] = vh.x; At[1][sj * 4 + 1][sn] = vh.y;
      At[1][sj * 4 + 2][sn] = vh.z; At[1][sj * 4 + 3][sn] = vh.w;
    }
#pragma unroll
    for (int i = 0; i < 6; ++i) {
      const int idx = tid + i * 256;
      const int row = idx / 96;
      const int c4 = idx - row * 96;
      *(float4*)&Bt[0][row][c4 * 4] = K4[(size_t)(k0 + row) * 96 + c4];
      *(float4*)&Bt[1][row][c4 * 4] = R4[(size_t)(k0 + row) * 96 + c4];
    }
    __syncthreads();

    for (int kk = 0; kk < 16; ++kk) {
      const float4 am4 = *(const float4*)&At[0][kk][ng * 4];
      const float4 ah4 = *(const float4*)&At[1][kk][ng * 4];
      const float am[4] = {am4.x, am4.y, am4.z, am4.w};
      const float ah[4] = {ah4.x, ah4.y, ah4.z, ah4.w};
      const int cb = cg * 8;
#pragma unroll
      for (int gset = 0; gset < 3; ++gset) {
        const int off = gset * 128 + cb;
        const float4 k0v = *(const float4*)&Bt[0][kk][off];
        const float4 k1v = *(const float4*)&Bt[0][kk][off + 4];
        const float4 r0v = *(const float4*)&Bt[1][kk][off];
        const float4 r1v = *(const float4*)&Bt[1][kk][off + 4];
        const float bk[8] = {k0v.x, k0v.y, k0v.z, k0v.w, k1v.x, k1v.y, k1v.z, k1v.w};
        const float br[8] = {r0v.x, r0v.y, r0v.z, r0v.w, r1v.x, r1v.y, r1v.z, r1v.w};
        if (gset == 0) {
#pragma unroll
          for (int n = 0; n < 4; ++n)
#pragma unroll
            for (int c = 0; c < 8; ++c) accZ[n][c] += am[n] * bk[c] + ah[n] * br[c];
        } else if (gset == 1) {
#pragma unroll
          for (int n = 0; n < 4; ++n)
#pragma unroll
            for (int c = 0; c < 8; ++c) accR[n][c] += am[n] * bk[c] + ah[n] * br[c];
        } else {
#pragma unroll
          for (int n = 0; n < 4; ++n)
#pragma unroll
            for (int c = 0; c < 8; ++c) {
              accXH[n][c] += am[n] * bk[c];
              accRH[n][c] += ah[n] * br[c];
            }
        }
      }
    }
  }

  const int cb = cg * 8;
#pragma unroll
  for (int n = 0; n < 4; ++n) {
    const int node = node0 + ng * 4 + n;
    if (node >= kNodes) continue;
    float o[8];
#pragma unroll
    for (int c = 0; c < 8; ++c) {
      const float z = sigf(accZ[n][c] + gb[cb + c] + gb[384 + cb + c]);
      const float r = sigf(accR[n][c] + gb[128 + cb + c] + gb[512 + cb + c]);
      const float hh = tanh_fast(accXH[n][c] + gb[256 + cb + c] +
                                 r * (accRH[n][c] + gb[640 + cb + c]));
      const float hp = hin[(size_t)node * kHid + cb + c];
      o[c] = z * hp + (1.f - z) * hh;
    }
    *(float4*)&hout[(size_t)node * kHid + cb]     = make_float4(o[0], o[1], o[2], o[3]);
    *(float4*)&hout[(size_t)node * kHid + cb + 4] = make_float4(o[4], o[5], o[6], o[7]);
  }
}

extern "C" void kernel_launch(void* const* d_in, const int* in_sizes, int n_in,
                              void* d_out, int out_size, void* d_ws, size_t ws_size,
                              hipStream_t stream) {
  const float* states = (const float*)d_in[0];
  const int*   edges  = (const int*)d_in[1];
  const float* W      = (const float*)d_in[2];
  const float* TB     = (const float*)d_in[3];
  const float* K      = (const float*)d_in[4];
  const float* R      = (const float*)d_in[5];
  const float* gb     = (const float*)d_in[6];
  float* out = (float*)d_out;

  if (ws_size < kWsFallback) return;

  char* ws = (char*)d_ws;
  int*      counts  = (int*)(ws + oCounts);
  int*      cursor  = (int*)(ws + oCursor);
  int*      bsums   = (int*)(ws + oBlockSums);
  uint16_t* bpack   = (uint16_t*)(ws + oBpack);
  unsigned* packed  = (unsigned*)(ws + oPacked);
  float*    msg     = (float*)(ws + oMsg);
  uint16_t* y16     = (uint16_t*)(ws + oY);
  uint32_t* y2      = (uint32_t*)(ws + oY);

  // --- build CSR by target
  hipMemsetAsync(counts, 0, 200704, stream);
  count_kernel<<<kEdges / 256, 256, 0, stream>>>(edges, counts);
  scan1_kernel<<<kScanBlocks, 256, 0, stream>>>(counts, cursor, bsums);
  scan2_kernel<<<1, 256, 0, stream>>>(bsums);
  scan3_kernel<<<kScanBlocks, 256, 0, stream>>>(cursor, bsums);
  fill_kernel<<<kEdges / 256, 256, 0, stream>>>(edges, cursor, packed);

  if (ws_size >= kWsNeeded) {
    pack_b_kernel<<<448, 256, 0, stream>>>(K, R, W, bpack);
    const int mfma_blocks = (kMT + 3) / 4;  // 782
    const int ga_blocks = kNodes / 4;       // 12500
    // step 1
    transform_mfma<<<mfma_blocks, 256, 0, stream>>>(states, bpack, TB, y16);
    gather_kernel<<<ga_blocks, 256, 0, stream>>>(y2, packed, cursor, counts, msg);
    gru_mfma<<<mfma_blocks, 256, 0, stream>>>(msg, states, bpack, gb, out);
    // step 2 (in-place on d_out)
    transform_mfma<<<mfma_blocks, 256, 0, stream>>>(out, bpack, TB, y16);
    gather_kernel<<<ga_blocks, 256, 0, stream>>>(y2, packed, cursor, counts, msg);
    gru_mfma<<<mfma_blocks, 256, 0, stream>>>(msg, out, bpack, gb, out);
  } else {
    const int msg_blocks = (kNodes + 31) / 32;  // 1563
    const int gru_blocks = (kNodes + 63) / 64;  // 782
    message_fb_kernel<<<msg_blocks, 256, 0, stream>>>(states, packed, cursor,
                                                      counts, W, TB, msg);
    gru_fb_kernel<<<gru_blocks, 256, 0, stream>>>(msg, states, K, R, gb, out);
    message_fb_kernel<<<msg_blocks, 256, 0, stream>>>(out, packed, cursor,
                                                      counts, W, TB, msg);
    gru_fb_kernel<<<gru_blocks, 256, 0, stream>>>(msg, out, K, R, gb, out);
  }
}

// Round 6
// 454.930 us; speedup vs baseline: 4.5638x; 1.3054x over previous
//
#include <hip/hip_runtime.h>
#include <stdint.h>

namespace {
constexpr int kNodes = 50000;
constexpr int kEdges = 800000;
constexpr int kHid   = 128;
constexpr int kScanBlocks = (kNodes + 255) / 256;  // 196
constexpr int kBlocks32 = (kNodes + 31) / 32;      // 1563

// workspace layout (bytes)
constexpr size_t oCounts    = 0;         // 200000 (in-degree per node)
constexpr size_t oCursor    = 200704;    // 200000 (scan -> row_end)
constexpr size_t oBlockSums = 401408;    // 784
constexpr size_t oBpack     = 402432;    // 655360 (packed MFMA B-frags)
constexpr size_t oPacked    = 1057792;   // 800000*4 = 3200000 (CSR edge list)
constexpr size_t oMsg       = 4257792;   // 50000*128*4 = 25600000 (fp32 msg)
constexpr size_t oY         = 29857792;  // 50000*512*2 = 51200000 (bf16 y)
constexpr size_t kWsNeeded   = oY + 51200000;  // 81,057,792
constexpr size_t kWsFallback = oY;             // fallback path doesn't use oY

// Bpack sub-offsets (bytes relative to oBpack)
constexpr size_t bKhi = 0,      bKlo = 98304,  bRhi = 196608,
                 bRlo = 294912, bWhi = 393216, bWlo = 524288;
}

typedef __attribute__((ext_vector_type(8))) short short8;
typedef __attribute__((ext_vector_type(4))) float f32x4;

union ABFrag { short8 v; uint16_t u[8]; uint4 q; };

__device__ __forceinline__ uint16_t f2bf(float x) {
  uint32_t u = __float_as_uint(x);
  return (uint16_t)((u + 0x7FFFu + ((u >> 16) & 1u)) >> 16);
}
__device__ __forceinline__ float bf2f(uint16_t h) {
  return __uint_as_float(((uint32_t)h) << 16);
}

// ---------------- CSR build ----------------

__global__ __launch_bounds__(256) void count_kernel(const int* __restrict__ edges,
                                                    int* __restrict__ counts) {
  int e = blockIdx.x * 256 + threadIdx.x;
  if (e < kEdges) atomicAdd(&counts[edges[e * 3 + 2]], 1);
}

__global__ __launch_bounds__(256) void scan1_kernel(const int* __restrict__ counts,
                                                    int* __restrict__ cursor,
                                                    int* __restrict__ blocksums) {
  __shared__ int sd[256];
  const int t = threadIdx.x;
  const int i = blockIdx.x * 256 + t;
  int v = (i < kNodes) ? counts[i] : 0;
  sd[t] = v;
  __syncthreads();
  for (int off = 1; off < 256; off <<= 1) {
    int x = (t >= off) ? sd[t - off] : 0;
    __syncthreads();
    sd[t] += x;
    __syncthreads();
  }
  if (i < kNodes) cursor[i] = sd[t] - v;
  if (t == 255) blocksums[blockIdx.x] = sd[255];
}

__global__ __launch_bounds__(256) void scan2_kernel(int* __restrict__ blocksums) {
  __shared__ int sd[256];
  const int t = threadIdx.x;
  int v = (t < kScanBlocks) ? blocksums[t] : 0;
  sd[t] = v;
  __syncthreads();
  for (int off = 1; off < 256; off <<= 1) {
    int x = (t >= off) ? sd[t - off] : 0;
    __syncthreads();
    sd[t] += x;
    __syncthreads();
  }
  if (t < kScanBlocks) blocksums[t] = sd[t] - v;
}

__global__ __launch_bounds__(256) void scan3_kernel(int* __restrict__ cursor,
                                                    const int* __restrict__ blocksums) {
  const int i = blockIdx.x * 256 + threadIdx.x;
  if (i < kNodes) cursor[i] += blocksums[blockIdx.x];
}

__global__ __launch_bounds__(256) void fill_kernel(const int* __restrict__ edges,
                                                   int* __restrict__ cursor,
                                                   unsigned* __restrict__ packed) {
  int e = blockIdx.x * 256 + threadIdx.x;
  if (e < kEdges) {
    const int et  = edges[e * 3 + 0];
    const int src = edges[e * 3 + 1];
    const int tgt = edges[e * 3 + 2];
    const int pos = atomicAdd(&cursor[tgt], 1);
    packed[pos] = (unsigned)(src * 4 + et);
  }
  // after this kernel cursor[v] = row_end(v)
}

// ---------------- pack B operands into MFMA-frag order ----------------
__global__ __launch_bounds__(256) void pack_b_kernel(
    const float* __restrict__ K,   // [128][384]
    const float* __restrict__ R,   // [128][384]
    const float* __restrict__ W,   // [4][128][128]
    uint16_t* __restrict__ bp) {
  const int idx = blockIdx.x * 256 + threadIdx.x;
  uint16_t* khi = bp + bKhi / 2;
  uint16_t* klo = bp + bKlo / 2;
  uint16_t* rhi = bp + bRhi / 2;
  uint16_t* rlo = bp + bRlo / 2;
  uint16_t* whi = bp + bWhi / 2;
  uint16_t* wlo = bp + bWlo / 2;
  if (idx < 128 * 384) {
    const int k = idx / 384, c = idx % 384;
    const int kt = k >> 5, quad = (k >> 3) & 3, j = k & 7;
    const int nt = c >> 4, ln = (c & 15) | (quad << 4);
    const size_t o = ((size_t)(kt * 24 + nt) * 64 + ln) * 8 + j;
    const float kv = K[k * 384 + c];
    const float rv = R[k * 384 + c];
    const uint16_t kh = f2bf(kv), rh = f2bf(rv);
    khi[o] = kh; klo[o] = f2bf(kv - bf2f(kh));
    rhi[o] = rh; rlo[o] = f2bf(rv - bf2f(rh));
  } else if (idx < 128 * 384 + 128 * 512) {
    const int i2 = idx - 128 * 384;
    const int k = i2 / 512, c = i2 % 512;
    const int t = c >> 7, cc = c & 127;
    const float wv = W[((size_t)t * 128 + k) * 128 + cc];
    const int kt = k >> 5, quad = (k >> 3) & 3, j = k & 7;
    const int nt = c >> 4, ln = (c & 15) | (quad << 4);
    const size_t o = ((size_t)(kt * 32 + nt) * 64 + ln) * 8 + j;
    const uint16_t wh = f2bf(wv);
    whi[o] = wh; wlo[o] = f2bf(wv - bf2f(wh));
  }
}

__device__ __forceinline__ void split8(const float* p, ABFrag& hi, ABFrag& lo) {
  const float4 a0 = *(const float4*)p;
  const float4 a1 = *(const float4*)(p + 4);
  const float v[8] = {a0.x, a0.y, a0.z, a0.w, a1.x, a1.y, a1.z, a1.w};
#pragma unroll
  for (int j = 0; j < 8; ++j) {
    const uint16_t t = f2bf(v[j]);
    hi.u[j] = t; lo.u[j] = f2bf(v[j] - bf2f(t));
  }
}

// ---------------- transform (MFMA): y = h @ W_t + TB, bf16 out ----------------
// block = 32 nodes x 512 cols; wave w = type w: 32 nodes (2 M-tiles) x 128 cols.
// No LDS, no barriers (h != y16, no in-place hazard). B-frag reuse across 2 M-tiles.
__global__ __launch_bounds__(256, 2) void transform_mfma(
    const float* __restrict__ h,       // [N][128]
    const uint16_t* __restrict__ bp,
    const float* __restrict__ TB,      // [512]
    uint16_t* __restrict__ y16) {      // [N][512] bf16 (bias included)
  const int tid = threadIdx.x;
  const int w = tid >> 6;              // type 0..3
  const int lane = tid & 63;
  const int col16 = lane & 15, quad = lane >> 4;
  const int node0 = blockIdx.x * 32;
  const bool m1ok = (node0 + 16) < kNodes;

  const uint4* __restrict__ Whi = (const uint4*)(bp + bWhi / 2);
  const uint4* __restrict__ Wlo = (const uint4*)(bp + bWlo / 2);

  f32x4 acc[8][2];
#pragma unroll
  for (int nt = 0; nt < 8; ++nt)
#pragma unroll
    for (int m = 0; m < 2; ++m) acc[nt][m] = (f32x4){0.f, 0.f, 0.f, 0.f};

  const float* hrow0 = h + (size_t)(node0 + col16) * kHid + quad * 8;
  const float* hrow1 = hrow0 + (size_t)16 * kHid;

#pragma unroll
  for (int kt = 0; kt < 4; ++kt) {
    ABFrag a0h, a0l, a1h, a1l;
    split8(hrow0 + kt * 32, a0h, a0l);
    if (m1ok) {
      split8(hrow1 + kt * 32, a1h, a1l);
    } else {
      a1h.q = make_uint4(0, 0, 0, 0); a1l.q = a1h.q;
    }
#pragma unroll
    for (int nt = 0; nt < 8; ++nt) {
      ABFrag bh, bl;
      bh.q = Whi[(size_t)(kt * 32 + w * 8 + nt) * 64 + lane];
      bl.q = Wlo[(size_t)(kt * 32 + w * 8 + nt) * 64 + lane];
      f32x4 c0 = acc[nt][0], c1 = acc[nt][1];
      c0 = __builtin_amdgcn_mfma_f32_16x16x32_bf16(a0h.v, bh.v, c0, 0, 0, 0);
      c1 = __builtin_amdgcn_mfma_f32_16x16x32_bf16(a1h.v, bh.v, c1, 0, 0, 0);
      c0 = __builtin_amdgcn_mfma_f32_16x16x32_bf16(a0h.v, bl.v, c0, 0, 0, 0);
      c1 = __builtin_amdgcn_mfma_f32_16x16x32_bf16(a1h.v, bl.v, c1, 0, 0, 0);
      c0 = __builtin_amdgcn_mfma_f32_16x16x32_bf16(a0l.v, bh.v, c0, 0, 0, 0);
      c1 = __builtin_amdgcn_mfma_f32_16x16x32_bf16(a1l.v, bh.v, c1, 0, 0, 0);
      acc[nt][0] = c0; acc[nt][1] = c1;
    }
  }

  // epilogue: C/D layout col = lane&15, row = quad*4 + reg
#pragma unroll
  for (int nt = 0; nt < 8; ++nt) {
    const int c = w * 128 + nt * 16 + col16;
    const float bias = TB[c];
#pragma unroll
    for (int r = 0; r < 4; ++r) {
      const int n0 = node0 + quad * 4 + r;
      y16[(size_t)n0 * 512 + c] = f2bf(acc[nt][0][r] + bias);
      if (m1ok) y16[(size_t)(n0 + 16) * 512 + c] = f2bf(acc[nt][1][r] + bias);
    }
  }
}

// ---------------- gather: msg[v] = sum_e y[src_e*4+t_e] ----------------
__global__ __launch_bounds__(256) void gather_kernel(
    const uint32_t* __restrict__ y2,      // y as uint32 pairs: [row][64]
    const uint32_t* __restrict__ packed,
    const int* __restrict__ rowend,
    const int* __restrict__ counts,
    float* __restrict__ msg) {
  const int tid = threadIdx.x;
  const int lane = tid & 63;
  const int v = blockIdx.x * 4 + (tid >> 6);
  const int cnt = counts[v];
  const int s0 = rowend[v] - cnt;
  float a0 = 0.f, a1 = 0.f;
  int e = 0;
  for (; e + 4 <= cnt; e += 4) {
    const uint32_t p0 = packed[s0 + e + 0];
    const uint32_t p1 = packed[s0 + e + 1];
    const uint32_t p2 = packed[s0 + e + 2];
    const uint32_t p3 = packed[s0 + e + 3];
    const uint32_t u0 = y2[(size_t)p0 * 64 + lane];
    const uint32_t u1 = y2[(size_t)p1 * 64 + lane];
    const uint32_t u2 = y2[(size_t)p2 * 64 + lane];
    const uint32_t u3 = y2[(size_t)p3 * 64 + lane];
    a0 += __uint_as_float(u0 << 16) + __uint_as_float(u1 << 16) +
          __uint_as_float(u2 << 16) + __uint_as_float(u3 << 16);
    a1 += __uint_as_float(u0 & 0xFFFF0000u) + __uint_as_float(u1 & 0xFFFF0000u) +
          __uint_as_float(u2 & 0xFFFF0000u) + __uint_as_float(u3 & 0xFFFF0000u);
  }
  for (; e < cnt; ++e) {
    const uint32_t p = packed[s0 + e];
    const uint32_t u = y2[(size_t)p * 64 + lane];
    a0 += __uint_as_float(u << 16);
    a1 += __uint_as_float(u & 0xFFFF0000u);
  }
  *(float2*)&msg[(size_t)v * kHid + lane * 2] = make_float2(a0, a1);
}

// ---------------- GRU (MFMA): wave = 32 nodes x 32 gate-cols, all 4 quantities ----------------
__device__ __forceinline__ float sigf(float x) { return 1.f / (1.f + __expf(-x)); }
__device__ __forceinline__ float tanh_fast(float x) {
  x = fminf(fmaxf(x, -15.f), 15.f);
  const float e2 = __expf(2.f * x);
  return (e2 - 1.f) / (e2 + 1.f);
}

// block = 32 nodes x 128 gate-cols (4 waves x 32 cols).
// IN-PLACE HAZARD (hin == hout on step 2): every wave READS all 32 rows of the
// block (A-fragments span K=0..127) but WRITES only its own 32-column slice.
// The __syncthreads() between the K-loop and the epilogue guarantees all
// waves' global reads of hin complete before any wave's epilogue stores
// (gfx950 __syncthreads drains vmcnt). Epilogue hp reads are wave-column-local.
__global__ __launch_bounds__(256, 2) void gru_mfma(
    const float* __restrict__ msg,     // [N][128]
    const float* __restrict__ hin,     // [N][128]
    const uint16_t* __restrict__ bp,
    const float* __restrict__ gb,      // [2][384]
    float* __restrict__ hout) {
  const int tid = threadIdx.x;
  const int w = tid >> 6;              // col-group: gate cols w*32..w*32+31
  const int lane = tid & 63;
  const int col16 = lane & 15, quad = lane >> 4;
  const int node0 = blockIdx.x * 32;
  const bool m1ok = (node0 + 16) < kNodes;

  const uint4* __restrict__ Khi = (const uint4*)(bp + bKhi / 2);
  const uint4* __restrict__ Klo = (const uint4*)(bp + bKlo / 2);
  const uint4* __restrict__ Rhi = (const uint4*)(bp + bRhi / 2);
  const uint4* __restrict__ Rlo = (const uint4*)(bp + bRlo / 2);

  f32x4 aZ[2][2], aR[2][2], aX[2][2], aH[2][2];  // [local nt][m]
#pragma unroll
  for (int i = 0; i < 2; ++i)
#pragma unroll
    for (int m = 0; m < 2; ++m) {
      aZ[i][m] = (f32x4){0.f, 0.f, 0.f, 0.f};
      aR[i][m] = aZ[i][m]; aX[i][m] = aZ[i][m]; aH[i][m] = aZ[i][m];
    }

  const float* mrow0 = msg + (size_t)(node0 + col16) * kHid + quad * 8;
  const float* hrow0 = hin + (size_t)(node0 + col16) * kHid + quad * 8;

  // epilogue hp values: read BEFORE the barrier would also work, but they are
  // wave-column-local so reading after the barrier is safe; keep after to
  // minimize register pressure in the K-loop.
#pragma unroll
  for (int kt = 0; kt < 4; ++kt) {
    ABFrag m0h, m0l, h0h, h0l, m1h, m1l, h1h, h1l;
    split8(mrow0 + kt * 32, m0h, m0l);
    split8(hrow0 + kt * 32, h0h, h0l);
    if (m1ok) {
      split8(mrow0 + 16 * kHid + kt * 32, m1h, m1l);
      split8(hrow0 + 16 * kHid + kt * 32, h1h, h1l);
    } else {
      m1h.q = make_uint4(0, 0, 0, 0); m1l.q = m1h.q;
      h1h.q = m1h.q; h1l.q = m1h.q;
    }
#pragma unroll
    for (int lnt = 0; lnt < 2; ++lnt) {
      const int ntc = w * 2 + lnt;           // 0..7
      const size_t oz = (size_t)(kt * 24 + ntc) * 64 + lane;
      const size_t orr = (size_t)(kt * 24 + 8 + ntc) * 64 + lane;
      const size_t oh = (size_t)(kt * 24 + 16 + ntc) * 64 + lane;
      ABFrag kzh, kzl, rzh, rzl, krh, krl, rrh, rrl, khh, khl, rhh, rhl;
      kzh.q = Khi[oz]; kzl.q = Klo[oz]; rzh.q = Rhi[oz]; rzl.q = Rlo[oz];
      krh.q = Khi[orr]; krl.q = Klo[orr]; rrh.q = Rhi[orr]; rrl.q = Rlo[orr];
      khh.q = Khi[oh]; khl.q = Klo[oh]; rhh.q = Rhi[oh]; rhl.q = Rlo[oh];

      // z gate: msg@K + h@R (fused)
      f32x4 z0 = aZ[lnt][0], z1 = aZ[lnt][1];
      z0 = __builtin_amdgcn_mfma_f32_16x16x32_bf16(m0h.v, kzh.v, z0, 0, 0, 0);
      z1 = __builtin_amdgcn_mfma_f32_16x16x32_bf16(m1h.v, kzh.v, z1, 0, 0, 0);
      z0 = __builtin_amdgcn_mfma_f32_16x16x32_bf16(m0h.v, kzl.v, z0, 0, 0, 0);
      z1 = __builtin_amdgcn_mfma_f32_16x16x32_bf16(m1h.v, kzl.v, z1, 0, 0, 0);
      z0 = __builtin_amdgcn_mfma_f32_16x16x32_bf16(m0l.v, kzh.v, z0, 0, 0, 0);
      z1 = __builtin_amdgcn_mfma_f32_16x16x32_bf16(m1l.v, kzh.v, z1, 0, 0, 0);
      z0 = __builtin_amdgcn_mfma_f32_16x16x32_bf16(h0h.v, rzh.v, z0, 0, 0, 0);
      z1 = __builtin_amdgcn_mfma_f32_16x16x32_bf16(h1h.v, rzh.v, z1, 0, 0, 0);
      z0 = __builtin_amdgcn_mfma_f32_16x16x32_bf16(h0h.v, rzl.v, z0, 0, 0, 0);
      z1 = __builtin_amdgcn_mfma_f32_16x16x32_bf16(h1h.v, rzl.v, z1, 0, 0, 0);
      z0 = __builtin_amdgcn_mfma_f32_16x16x32_bf16(h0l.v, rzh.v, z0, 0, 0, 0);
      z1 = __builtin_amdgcn_mfma_f32_16x16x32_bf16(h1l.v, rzh.v, z1, 0, 0, 0);
      aZ[lnt][0] = z0; aZ[lnt][1] = z1;

      // r gate (fused)
      f32x4 r0 = aR[lnt][0], r1 = aR[lnt][1];
      r0 = __builtin_amdgcn_mfma_f32_16x16x32_bf16(m0h.v, krh.v, r0, 0, 0, 0);
      r1 = __builtin_amdgcn_mfma_f32_16x16x32_bf16(m1h.v, krh.v, r1, 0, 0, 0);
      r0 = __builtin_amdgcn_mfma_f32_16x16x32_bf16(m0h.v, krl.v, r0, 0, 0, 0);
      r1 = __builtin_amdgcn_mfma_f32_16x16x32_bf16(m1h.v, krl.v, r1, 0, 0, 0);
      r0 = __builtin_amdgcn_mfma_f32_16x16x32_bf16(m0l.v, krh.v, r0, 0, 0, 0);
      r1 = __builtin_amdgcn_mfma_f32_16x16x32_bf16(m1l.v, krh.v, r1, 0, 0, 0);
      r0 = __builtin_amdgcn_mfma_f32_16x16x32_bf16(h0h.v, rrh.v, r0, 0, 0, 0);
      r1 = __builtin_amdgcn_mfma_f32_16x16x32_bf16(h1h.v, rrh.v, r1, 0, 0, 0);
      r0 = __builtin_amdgcn_mfma_f32_16x16x32_bf16(h0h.v, rrl.v, r0, 0, 0, 0);
      r1 = __builtin_amdgcn_mfma_f32_16x16x32_bf16(h1h.v, rrl.v, r1, 0, 0, 0);
      r0 = __builtin_amdgcn_mfma_f32_16x16x32_bf16(h0l.v, rrh.v, r0, 0, 0, 0);
      r1 = __builtin_amdgcn_mfma_f32_16x16x32_bf16(h1l.v, rrh.v, r1, 0, 0, 0);
      aR[lnt][0] = r0; aR[lnt][1] = r1;

      // h gate: xh = msg@K, rh = h@R (kept separate)
      f32x4 x0 = aX[lnt][0], x1 = aX[lnt][1];
      x0 = __builtin_amdgcn_mfma_f32_16x16x32_bf16(m0h.v, khh.v, x0, 0, 0, 0);
      x1 = __builtin_amdgcn_mfma_f32_16x16x32_bf16(m1h.v, khh.v, x1, 0, 0, 0);
      x0 = __builtin_amdgcn_mfma_f32_16x16x32_bf16(m0h.v, khl.v, x0, 0, 0, 0);
      x1 = __builtin_amdgcn_mfma_f32_16x16x32_bf16(m1h.v, khl.v, x1, 0, 0, 0);
      x0 = __builtin_amdgcn_mfma_f32_16x16x32_bf16(m0l.v, khh.v, x0, 0, 0, 0);
      x1 = __builtin_amdgcn_mfma_f32_16x16x32_bf16(m1l.v, khh.v, x1, 0, 0, 0);
      aX[lnt][0] = x0; aX[lnt][1] = x1;

      f32x4 y0 = aH[lnt][0], y1 = aH[lnt][1];
      y0 = __builtin_amdgcn_mfma_f32_16x16x32_bf16(h0h.v, rhh.v, y0, 0, 0, 0);
      y1 = __builtin_amdgcn_mfma_f32_16x16x32_bf16(h1h.v, rhh.v, y1, 0, 0, 0);
      y0 = __builtin_amdgcn_mfma_f32_16x16x32_bf16(h0h.v, rhl.v, y0, 0, 0, 0);
      y1 = __builtin_amdgcn_mfma_f32_16x16x32_bf16(h1h.v, rhl.v, y1, 0, 0, 0);
      y0 = __builtin_amdgcn_mfma_f32_16x16x32_bf16(h0l.v, rhh.v, y0, 0, 0, 0);
      y1 = __builtin_amdgcn_mfma_f32_16x16x32_bf16(h1l.v, rhh.v, y1, 0, 0, 0);
      aH[lnt][0] = y0; aH[lnt][1] = y1;
    }
  }

  // all waves' reads of hin are complete past this point (vmcnt drained)
  __syncthreads();

  // ---- epilogue (wave-column-local)
#pragma unroll
  for (int lnt = 0; lnt < 2; ++lnt) {
    const int c = (w * 2 + lnt) * 16 + col16;
    const float bz = gb[c] + gb[384 + c];
    const float br = gb[128 + c] + gb[512 + c];
    const float bx = gb[256 + c];
    const float bh = gb[640 + c];
#pragma unroll
    for (int m = 0; m < 2; ++m) {
      if (m == 1 && !m1ok) break;
#pragma unroll
      for (int r = 0; r < 4; ++r) {
        const int node = node0 + m * 16 + quad * 4 + r;
        const float hp = hin[(size_t)node * kHid + c];
        const float z = sigf(aZ[lnt][m][r] + bz);
        const float rr = sigf(aR[lnt][m][r] + br);
        const float hh = tanh_fast(aX[lnt][m][r] + bx + rr * (aH[lnt][m][r] + bh));
        hout[(size_t)node * kHid + c] = z * hp + (1.f - z) * hh;
      }
    }
  }
}

// ---------------- fallback path (only if ws too small) ----------------

__global__ __launch_bounds__(256, 2) void message_fb_kernel(
    const float* __restrict__ hin,
    const unsigned* __restrict__ packed,
    const int* __restrict__ rowend,
    const int* __restrict__ counts,
    const float* __restrict__ W,
    const float* __restrict__ TB,
    float* __restrict__ msg) {
  __shared__ float S[32 * 512];
  __shared__ int D[32][4];
  const int tid = threadIdx.x;
  {
    const int g = tid >> 7;
    const int j = tid & 127;
    for (int i = 0; i < 16; ++i) {
      const int nl = g * 16 + i;
      const int v = blockIdx.x * 32 + nl;
      if (v >= kNodes) break;
      const int cnt = counts[v];
      const int s0 = rowend[v] - cnt;
      float a0 = 0.f, a1 = 0.f, a2 = 0.f, a3 = 0.f;
      int d0 = 0, d1 = 0, d2 = 0, d3 = 0;
      for (int e = 0; e < cnt; ++e) {
        const unsigned p = packed[s0 + e];
        const int src = (int)(p >> 2);
        const int t = (int)(p & 3u);
        const float val = hin[(size_t)src * kHid + j];
        a0 += (t == 0) ? val : 0.f;
        a1 += (t == 1) ? val : 0.f;
        a2 += (t == 2) ? val : 0.f;
        a3 += (t == 3) ? val : 0.f;
        d0 += (t == 0); d1 += (t == 1); d2 += (t == 2); d3 += (t == 3);
      }
      float* Sn = &S[nl * 512];
      Sn[j] = a0; Sn[128 + j] = a1; Sn[256 + j] = a2; Sn[384 + j] = a3;
      if (j == 0) { D[nl][0] = d0; D[nl][1] = d1; D[nl][2] = d2; D[nl][3] = d3; }
    }
  }
  __syncthreads();

  const int lane = tid & 31;
  const int jj = lane * 4;
  const int n0 = (tid >> 5) * 4;
  float acc[4][4] = {};
  const float4* __restrict__ W4 = (const float4*)W;
  for (int tk = 0; tk < 512; tk += 4) {
    const float4 w0 = W4[(size_t)(tk + 0) * 32 + lane];
    const float4 w1 = W4[(size_t)(tk + 1) * 32 + lane];
    const float4 w2 = W4[(size_t)(tk + 2) * 32 + lane];
    const float4 w3 = W4[(size_t)(tk + 3) * 32 + lane];
#pragma unroll
    for (int n = 0; n < 4; ++n) {
      const float4 s = *(const float4*)&S[(n0 + n) * 512 + tk];
      acc[n][0] += s.x * w0.x + s.y * w1.x + s.z * w2.x + s.w * w3.x;
      acc[n][1] += s.x * w0.y + s.y * w1.y + s.z * w2.y + s.w * w3.y;
      acc[n][2] += s.x * w0.z + s.y * w1.z + s.z * w2.z + s.w * w3.z;
      acc[n][3] += s.x * w0.w + s.y * w1.w + s.z * w2.w + s.w * w3.w;
    }
  }
  const float4 B0 = *(const float4*)&TB[0 * 128 + jj];
  const float4 B1 = *(const float4*)&TB[1 * 128 + jj];
  const float4 B2 = *(const float4*)&TB[2 * 128 + jj];
  const float4 B3 = *(const float4*)&TB[3 * 128 + jj];
#pragma unroll
  for (int n = 0; n < 4; ++n) {
    const int v = blockIdx.x * 32 + n0 + n;
    if (v < kNodes) {
      float4 o;
      const float d0 = (float)D[n0 + n][0], d1 = (float)D[n0 + n][1];
      const float d2 = (float)D[n0 + n][2], d3 = (float)D[n0 + n][3];
      o.x = acc[n][0] + d0 * B0.x + d1 * B1.x + d2 * B2.x + d3 * B3.x;
      o.y = acc[n][1] + d0 * B0.y + d1 * B1.y + d2 * B2.y + d3 * B3.y;
      o.z = acc[n][2] + d0 * B0.z + d1 * B1.z + d2 * B2.z + d3 * B3.z;
      o.w = acc[n][3] + d0 * B0.w + d1 * B1.w + d2 * B2.w + d3 * B3.w;
      *(float4*)&msg[(size_t)v * kHid + jj] = o;
    }
  }
}

__global__ __launch_bounds__(256, 2) void gru_fb_kernel(
    const float* __restrict__ msg,
    const float* __restrict__ hin,
    const float* __restrict__ K,
    const float* __restrict__ R,
    const float* __restrict__ gb,
    float* __restrict__ hout) {
  __shared__ float At[2][16][68];
  __shared__ float Bt[2][16][384];
  const int tid = threadIdx.x;
  const int node0 = blockIdx.x * 64;
  const int cg = tid >> 4;
  const int ng = tid & 15;

  float accZ[4][8] = {}, accR[4][8] = {}, accXH[4][8] = {}, accRH[4][8] = {};
  const float4* __restrict__ K4 = (const float4*)K;
  const float4* __restrict__ R4 = (const float4*)R;
  const int sn = tid >> 2;
  const int sj = tid & 3;

  for (int k0 = 0; k0 < 128; k0 += 16) {
    __syncthreads();
    {
      float4 vm = make_float4(0.f, 0.f, 0.f, 0.f);
      float4 vh = vm;
      const int node = node0 + sn;
      if (node < kNodes) {
        vm = *(const float4*)&msg[(size_t)node * kHid + k0 + sj * 4];
        vh = *(const float4*)&hin[(size_t)node * kHid + k0 + sj * 4];
      }
      At[0][sj * 4 + 0][sn] = vm.x; At[0][sj * 4 + 1][sn] = vm.y;
      At[0][sj * 4 + 2][sn] = vm.z; At[0][sj * 4 + 3][sn] = vm.w;
      At[1][sj * 4 + 0][sn] = vh.x; At[1][sj * 4 + 1][sn] = vh.y;
      At[1][sj * 4 + 2][sn] = vh.z; At[1][sj * 4 + 3][sn] = vh.w;
    }
#pragma unroll
    for (int i = 0; i < 6; ++i) {
      const int idx = tid + i * 256;
      const int row = idx / 96;
      const int c4 = idx - row * 96;
      *(float4*)&Bt[0][row][c4 * 4] = K4[(size_t)(k0 + row) * 96 + c4];
      *(float4*)&Bt[1][row][c4 * 4] = R4[(size_t)(k0 + row) * 96 + c4];
    }
    __syncthreads();

    for (int kk = 0; kk < 16; ++kk) {
      const float4 am4 = *(const float4*)&At[0][kk][ng * 4];
      const float4 ah4 = *(const float4*)&At[1][kk][ng * 4];
      const float am[4] = {am4.x, am4.y, am4.z, am4.w};
      const float ah[4] = {ah4.x, ah4.y, ah4.z, ah4.w};
      const int cb = cg * 8;
#pragma unroll
      for (int gset = 0; gset < 3; ++gset) {
        const int off = gset * 128 + cb;
        const float4 k0v = *(const float4*)&Bt[0][kk][off];
        const float4 k1v = *(const float4*)&Bt[0][kk][off + 4];
        const float4 r0v = *(const float4*)&Bt[1][kk][off];
        const float4 r1v = *(const float4*)&Bt[1][kk][off + 4];
        const float bk[8] = {k0v.x, k0v.y, k0v.z, k0v.w, k1v.x, k1v.y, k1v.z, k1v.w};
        const float br[8] = {r0v.x, r0v.y, r0v.z, r0v.w, r1v.x, r1v.y, r1v.z, r1v.w};
        if (gset == 0) {
#pragma unroll
          for (int n = 0; n < 4; ++n)
#pragma unroll
            for (int c = 0; c < 8; ++c) accZ[n][c] += am[n] * bk[c] + ah[n] * br[c];
        } else if (gset == 1) {
#pragma unroll
          for (int n = 0; n < 4; ++n)
#pragma unroll
            for (int c = 0; c < 8; ++c) accR[n][c] += am[n] * bk[c] + ah[n] * br[c];
        } else {
#pragma unroll
          for (int n = 0; n < 4; ++n)
#pragma unroll
            for (int c = 0; c < 8; ++c) {
              accXH[n][c] += am[n] * bk[c];
              accRH[n][c] += ah[n] * br[c];
            }
        }
      }
    }
  }

  const int cb = cg * 8;
#pragma unroll
  for (int n = 0; n < 4; ++n) {
    const int node = node0 + ng * 4 + n;
    if (node >= kNodes) continue;
    float o[8];
#pragma unroll
    for (int c = 0; c < 8; ++c) {
      const float z = sigf(accZ[n][c] + gb[cb + c] + gb[384 + cb + c]);
      const float r = sigf(accR[n][c] + gb[128 + cb + c] + gb[512 + cb + c]);
      const float hh = tanh_fast(accXH[n][c] + gb[256 + cb + c] +
                                 r * (accRH[n][c] + gb[640 + cb + c]));
      const float hp = hin[(size_t)node * kHid + cb + c];
      o[c] = z * hp + (1.f - z) * hh;
    }
    *(float4*)&hout[(size_t)node * kHid + cb]     = make_float4(o[0], o[1], o[2], o[3]);
    *(float4*)&hout[(size_t)node * kHid + cb + 4] = make_float4(o[4], o[5], o[6], o[7]);
  }
}

extern "C" void kernel_launch(void* const* d_in, const int* in_sizes, int n_in,
                              void* d_out, int out_size, void* d_ws, size_t ws_size,
                              hipStream_t stream) {
  const float* states = (const float*)d_in[0];
  const int*   edges  = (const int*)d_in[1];
  const float* W      = (const float*)d_in[2];
  const float* TB     = (const float*)d_in[3];
  const float* K      = (const float*)d_in[4];
  const float* R      = (const float*)d_in[5];
  const float* gb     = (const float*)d_in[6];
  float* out = (float*)d_out;

  if (ws_size < kWsFallback) return;

  char* ws = (char*)d_ws;
  int*      counts  = (int*)(ws + oCounts);
  int*      cursor  = (int*)(ws + oCursor);
  int*      bsums   = (int*)(ws + oBlockSums);
  uint16_t* bpack   = (uint16_t*)(ws + oBpack);
  unsigned* packed  = (unsigned*)(ws + oPacked);
  float*    msg     = (float*)(ws + oMsg);
  uint16_t* y16     = (uint16_t*)(ws + oY);
  uint32_t* y2      = (uint32_t*)(ws + oY);

  hipMemsetAsync(counts, 0, 200704, stream);
  count_kernel<<<kEdges / 256, 256, 0, stream>>>(edges, counts);
  scan1_kernel<<<kScanBlocks, 256, 0, stream>>>(counts, cursor, bsums);
  scan2_kernel<<<1, 256, 0, stream>>>(bsums);
  scan3_kernel<<<kScanBlocks, 256, 0, stream>>>(cursor, bsums);
  fill_kernel<<<kEdges / 256, 256, 0, stream>>>(edges, cursor, packed);

  if (ws_size >= kWsNeeded) {
    pack_b_kernel<<<448, 256, 0, stream>>>(K, R, W, bpack);
    const int ga_blocks = kNodes / 4;  // 12500
    // step 1
    transform_mfma<<<kBlocks32, 256, 0, stream>>>(states, bpack, TB, y16);
    gather_kernel<<<ga_blocks, 256, 0, stream>>>(y2, packed, cursor, counts, msg);
    gru_mfma<<<kBlocks32, 256, 0, stream>>>(msg, states, bpack, gb, out);
    // step 2 (in-place on d_out; see gru_mfma barrier note)
    transform_mfma<<<kBlocks32, 256, 0, stream>>>(out, bpack, TB, y16);
    gather_kernel<<<ga_blocks, 256, 0, stream>>>(y2, packed, cursor, counts, msg);
    gru_mfma<<<kBlocks32, 256, 0, stream>>>(msg, out, bpack, gb, out);
  } else {
    const int msg_blocks = (kNodes + 31) / 32;  // 1563
    const int gru_blocks = (kNodes + 63) / 64;  // 782
    message_fb_kernel<<<msg_blocks, 256, 0, stream>>>(states, packed, cursor,
                                                      counts, W, TB, msg);
    gru_fb_kernel<<<gru_blocks, 256, 0, stream>>>(msg, states, K, R, gb, out);
    message_fb_kernel<<<msg_blocks, 256, 0, stream>>>(out, packed, cursor,
                                                      counts, W, TB, msg);
    gru_fb_kernel<<<gru_blocks, 256, 0, stream>>>(msg, out, K, R, gb, out);
  }
}